// Round 18
// baseline (209.713 us; speedup 1.0000x reference)
//
#include <hip/hip_runtime.h>

// ---------------------------------------------------------------------------
// MQA: out = softmax((X Wq)(X Wk)^T / 32)(X Wv) Wo, MQA broadcast K/V.
// B=2, S=2048, IN=HID=1024, H=16, D=64.
// Round 26 (from R24 = 197.2us verified; R25 XCD map neutral -> reverted):
// Ledger: non-mqa time invariant at ~155us across SIX GEMM structures ->
// GEMM internals are not the determinant. Lever: delete the xq_bf
// dependency. Q-proj's A-path now converts query fp32->bf16 INLINE
// (verified gemm64<true> pattern: reg-load 2x float4 -> 4x cvt_pk ->
// ds_write_b128 replicating gload_lds's exact linear layout
// [seg i][lane*16B]); fp32 loads issued before the MFMA block, converted/
// written after (latency overlap; +32 transient VGPR ~= 108 < 128 cap).
// prep_w loses its 1024 query-conversion blocks (grid 1568 -> 544) and
// ~32MB of traffic. out_proj keeps the bf16 gload_lds A-path.
// gemm64 / mqa (frozen R21) byte-identical.
// ---------------------------------------------------------------------------

typedef unsigned int   u32;
typedef unsigned short u16;
typedef union { float4 v; float f[4]; } f4u;
typedef __attribute__((ext_vector_type(8)))  short frag16;  // 8 bf16 (4 VGPR)
typedef __attribute__((ext_vector_type(4)))  float f32x4;
typedef __attribute__((ext_vector_type(16))) float f32x16;  // 32x32 MFMA acc
typedef union { frag16 v; u32 w[4]; u16 e[8]; } bf8u;

static __device__ __forceinline__ u16 f2bf(float x) {
  union { float f; u32 u; } v; v.f = x;
  u32 r = v.u + 0x7fff + ((v.u >> 16) & 1);   // RNE
  return (u16)(r >> 16);
}

// HW packed f32x2 -> bf16x2 convert (RNE), inline asm (no builtin on gfx950).
static __device__ __forceinline__ u32 cvt_pk_bf16(float lo, float hi) {
  u32 r;
  asm("v_cvt_pk_bf16_f32 %0, %1, %2" : "=v"(r) : "v"(lo), "v"(hi));
  return r;
}

// In-place 32-lane-half swap (pure VALU, no LDS):
// after: a = [a_lo | b_lo], b = [a_hi | b_hi].  (R19-verified)
static __device__ __forceinline__ void pl32_swap(u32& a, u32& b) {
  asm volatile("v_permlane32_swap_b32 %0, %1" : "+v"(a), "+v"(b));
}

// Async global->LDS, 16B per lane. LDS dest = wave-uniform base + lane*16.
static __device__ __forceinline__ void gload_lds16(const u16* g, u16* l) {
  __builtin_amdgcn_global_load_lds(
      (const __attribute__((address_space(1))) u32*)g,
      (__attribute__((address_space(3))) u32*)l, 16, 0, 0);
}

// ---------------------------------------------------------------------------
// prep_w: weight transpose+convert tiles ONLY (544 blocks; query conversion
// now inline in proj2's Q-proj A-path).
// ---------------------------------------------------------------------------
static __device__ void tcvt_tile(const float* __restrict__ src,
                                 u16* __restrict__ dst,
                                 int C, int ldT, int rt, int ct,
                                 float (*t)[65]) {
  const int r0 = rt * 64, c0 = ct * 64;
  const int tr  = threadIdx.x >> 4;
  const int tc4 = (threadIdx.x & 15) * 4;
#pragma unroll
  for (int i = 0; i < 4; ++i) {
    f4u v; v.v = *(const float4*)(src + (size_t)(r0 + tr + i * 16) * C + c0 + tc4);
    t[tr + i * 16][tc4 + 0] = v.f[0];
    t[tr + i * 16][tc4 + 1] = v.f[1];
    t[tr + i * 16][tc4 + 2] = v.f[2];
    t[tr + i * 16][tc4 + 3] = v.f[3];
  }
  __syncthreads();
#pragma unroll
  for (int i = 0; i < 4; ++i) {
    const int oc = tr + i * 16;
    ushort4 o;
    o.x = f2bf(t[tc4 + 0][oc]);
    o.y = f2bf(t[tc4 + 1][oc]);
    o.z = f2bf(t[tc4 + 2][oc]);
    o.w = f2bf(t[tc4 + 3][oc]);
    *(ushort4*)(dst + (size_t)(c0 + oc) * ldT + r0 + tc4) = o;
  }
}

__global__ __launch_bounds__(256)
void prep_w(const float* __restrict__ Wq, const float* __restrict__ Wo,
            const float* __restrict__ Wk, const float* __restrict__ Wv,
            u16* __restrict__ wq_t, u16* __restrict__ wo_t,
            u16* __restrict__ wk_t, u16* __restrict__ wv_t) {
  const int bid = blockIdx.x;
  __shared__ float t[64][65];
  if (bid < 256)      tcvt_tile(Wq, wq_t, 1024, 1024, bid >> 4, bid & 15, t);
  else if (bid < 512) tcvt_tile(Wo, wo_t, 1024, 1024, (bid - 256) >> 4, (bid - 256) & 15, t);
  else if (bid < 528) tcvt_tile(Wk, wk_t, 64, 1024, bid - 512, 0, t);
  else                tcvt_tile(Wv, wv_t, 64, 1024, bid - 528, 0, t);
}

// ---------------------------------------------------------------------------
// gemm128n64<A_FP32>: 128x64-tile bf16 GEMM, BK=64, pipelined K-loop
// (R24-verified shape). C = A[M,K] . Bt[N,K]^T. 256 thr = 4 waves (2x2).
// A_FP32=true: A staged via reg-load fp32 -> cvt_pk -> ds_write_b128,
// replicating gload_lds's linear layout (dest alds + i*512 + lane*8 u16;
// src (row0+w*32+i*8+lrow)*K + lcol, 8 consecutive k as 2x float4).
// A_FP32=false: A staged via gload_lds (R24 path). B always gload_lds.
// ---------------------------------------------------------------------------
template <bool A_FP32>
static __device__ void gemm128n64(const float* __restrict__ Af32,
                                  const u16* __restrict__ Abf,
                                  const u16* __restrict__ Bt,
                                  const float* __restrict__ bias,
                                  void* __restrict__ Cout, int out_mode,
                                  float oscale, int row0, int col0,
                                  int N, int K, u16* As, u16* Bs) {
  const int tid  = threadIdx.x;
  const int lane = tid & 63;
  const int quad = lane >> 4, l15 = lane & 15;
  const int w = tid >> 6, wy = w >> 1, wx = w & 1;
  const int lrow = lane >> 3, lcol = (lane & 7) * 8;

  f32x4 acc[4][2];
#pragma unroll
  for (int i = 0; i < 4; ++i)
#pragma unroll
    for (int j = 0; j < 2; ++j) {
      acc[i][j][0] = 0.f; acc[i][j][1] = 0.f;
      acc[i][j][2] = 0.f; acc[i][j][3] = 0.f;
    }

  const u16*   agb = A_FP32 ? nullptr
                            : Abf + (size_t)(row0 + w * 32 + lrow) * K + lcol;
  const float* agf = A_FP32 ? Af32 + (size_t)(row0 + w * 32 + lrow) * K + lcol
                            : nullptr;
  const u16* bg = Bt + (size_t)(col0 + w * 16 + lrow) * K + lcol;
  u16* alds = As + w * 4 * 512;   // wave-uniform segment base (A: segs 4w..4w+3)
  u16* blds = Bs + w * 2 * 512;   // B: segs 2w..2w+1
  u16* aw = alds + lane * 8;      // this lane's A dest (16B), = gload_lds layout

  // prologue: stage step 0
  if (A_FP32) {
#pragma unroll
    for (int i = 0; i < 4; ++i) {
      const float* ap = agf + (size_t)i * 8 * K;
      f4u x0, x1;
      x0.v = *(const float4*)(ap);
      x1.v = *(const float4*)(ap + 4);
      bf8u t;
      t.w[0] = cvt_pk_bf16(x0.f[0], x0.f[1]);
      t.w[1] = cvt_pk_bf16(x0.f[2], x0.f[3]);
      t.w[2] = cvt_pk_bf16(x1.f[0], x1.f[1]);
      t.w[3] = cvt_pk_bf16(x1.f[2], x1.f[3]);
      *(frag16*)(aw + i * 512) = t.v;
    }
  } else {
#pragma unroll
    for (int i = 0; i < 4; ++i)
      gload_lds16(agb + (size_t)i * 8 * K, alds + i * 512);
  }
#pragma unroll
  for (int i = 0; i < 2; ++i)
    gload_lds16(bg + (size_t)i * 8 * K, blds + i * 512);
  __syncthreads();   // step-0 staging visible

  for (int k0 = 0; k0 < K; k0 += 64) {
    // ---- 1. read all fragments of step t into registers ----
    frag16 af[2][4], bfr[2][2];
#pragma unroll
    for (int ks = 0; ks < 2; ++ks) {
#pragma unroll
      for (int i = 0; i < 4; ++i)
        af[ks][i] = *(const frag16*)(&As[(wy * 64 + i * 16 + l15) * 64 + ks * 32 + quad * 8]);
#pragma unroll
      for (int j = 0; j < 2; ++j)
        bfr[ks][j] = *(const frag16*)(&Bs[(wx * 32 + j * 16 + l15) * 64 + ks * 32 + quad * 8]);
    }
    __syncthreads();   // all waves done reading LDS (WAR for next stage)

    const bool more = (k0 + 64 < K);

    // ---- 2. issue next step's loads (latency hides under compute) ----
    f4u x[4][2];
    if (more) {
      if (A_FP32) {
#pragma unroll
        for (int i = 0; i < 4; ++i) {
          const float* ap = agf + (size_t)i * 8 * K + k0 + 64;
          x[i][0].v = *(const float4*)(ap);
          x[i][1].v = *(const float4*)(ap + 4);
        }
      } else {
#pragma unroll
        for (int i = 0; i < 4; ++i)
          gload_lds16(agb + (size_t)i * 8 * K + k0 + 64, alds + i * 512);
      }
#pragma unroll
      for (int i = 0; i < 2; ++i)
        gload_lds16(bg + (size_t)i * 8 * K + k0 + 64, blds + i * 512);
    }

    // ---- 3. compute from registers (no LDS access) ----
#pragma unroll
    for (int ks = 0; ks < 2; ++ks)
#pragma unroll
      for (int i = 0; i < 4; ++i)
#pragma unroll
        for (int j = 0; j < 2; ++j)
          acc[i][j] = __builtin_amdgcn_mfma_f32_16x16x32_bf16(af[ks][i], bfr[ks][j], acc[i][j], 0, 0, 0);

    // ---- 4. convert + write next A step (A_FP32 path) ----
    if (A_FP32 && more) {
#pragma unroll
      for (int i = 0; i < 4; ++i) {
        bf8u t;
        t.w[0] = cvt_pk_bf16(x[i][0].f[0], x[i][0].f[1]);
        t.w[1] = cvt_pk_bf16(x[i][0].f[2], x[i][0].f[3]);
        t.w[2] = cvt_pk_bf16(x[i][1].f[0], x[i][1].f[1]);
        t.w[3] = cvt_pk_bf16(x[i][1].f[2], x[i][1].f[3]);
        *(frag16*)(aw + i * 512) = t.v;
      }
    }

    __syncthreads();   // drains vmcnt/lgkmcnt -> step t+1 staged
  }

  float bj[2];
#pragma unroll
  for (int j = 0; j < 2; ++j)
    bj[j] = bias[col0 + wx * 32 + j * 16 + l15];

#pragma unroll
  for (int i = 0; i < 4; ++i)
#pragma unroll
    for (int rr = 0; rr < 4; ++rr) {
      const size_t row = row0 + wy * 64 + i * 16 + quad * 4 + rr;
#pragma unroll
      for (int j = 0; j < 2; ++j) {
        const float v = (acc[i][j][rr] + bj[j]) * oscale;
        const int col = col0 + wx * 32 + j * 16 + l15;
        if (out_mode == 0) ((float*)Cout)[row * N + col] = v;
        else               ((u16*)Cout)[row * N + col] = f2bf(v);
      }
    }
}

// ---------------------------------------------------------------------------
// gemm64: 64x64-tile GEMM (kept for the N=64 K/V projections; fp32 A path).
// ---------------------------------------------------------------------------
#define GP 72
template <bool A_FP32>
static __device__ void gemm64(const float* __restrict__ Af32,
                              const u16* __restrict__ Abf,
                              const u16* __restrict__ Bt,
                              const float* __restrict__ bias,
                              void* __restrict__ Cout, int out_mode,
                              float oscale,
                              int row0, int col0, int N, int K, int ldT,
                              u16* As, u16* Bs) {
  const int tid  = threadIdx.x;
  const int lane = tid & 63;
  const int quad = lane >> 4, l15 = lane & 15;
  const int w = tid >> 6, wy = w >> 1, wx = w & 1;

  f32x4 acc[2][2];
#pragma unroll
  for (int i = 0; i < 2; ++i)
#pragma unroll
    for (int j = 0; j < 2; ++j) {
      acc[i][j][0] = 0.f; acc[i][j][1] = 0.f;
      acc[i][j][2] = 0.f; acc[i][j][3] = 0.f;
    }

  const int r = tid >> 2, c16 = (tid & 3) * 16;

  for (int k0 = 0; k0 < K; k0 += 64) {
    frag16 a0, a1;
    if (A_FP32) {
      const float* ap = Af32 + (size_t)(row0 + r) * K + k0 + c16;
      f4u x0, x1, x2, x3;
      x0.v = *(const float4*)(ap);
      x1.v = *(const float4*)(ap + 4);
      x2.v = *(const float4*)(ap + 8);
      x3.v = *(const float4*)(ap + 12);
      bf8u t0, t1;
      t0.w[0] = cvt_pk_bf16(x0.f[0], x0.f[1]);
      t0.w[1] = cvt_pk_bf16(x0.f[2], x0.f[3]);
      t0.w[2] = cvt_pk_bf16(x1.f[0], x1.f[1]);
      t0.w[3] = cvt_pk_bf16(x1.f[2], x1.f[3]);
      t1.w[0] = cvt_pk_bf16(x2.f[0], x2.f[1]);
      t1.w[1] = cvt_pk_bf16(x2.f[2], x2.f[3]);
      t1.w[2] = cvt_pk_bf16(x3.f[0], x3.f[1]);
      t1.w[3] = cvt_pk_bf16(x3.f[2], x3.f[3]);
      a0 = t0.v; a1 = t1.v;
    } else {
      const u16* ap = Abf + (size_t)(row0 + r) * K + k0 + c16;
      a0 = *(const frag16*)(ap);
      a1 = *(const frag16*)(ap + 8);
    }
    const u16* bp = Bt + (size_t)(col0 + r) * K + k0 + c16;
    const frag16 b0 = *(const frag16*)(bp);
    const frag16 b1 = *(const frag16*)(bp + 8);
    __syncthreads();
    *(frag16*)(&As[r * GP + c16])     = a0;
    *(frag16*)(&As[r * GP + c16 + 8]) = a1;
    *(frag16*)(&Bs[r * GP + c16])     = b0;
    *(frag16*)(&Bs[r * GP + c16 + 8]) = b1;
    __syncthreads();
#pragma unroll
    for (int ks = 0; ks < 2; ++ks) {
      frag16 af[2], bf[2];
#pragma unroll
      for (int i = 0; i < 2; ++i)
        af[i] = *(const frag16*)(&As[(wy * 32 + i * 16 + l15) * GP + ks * 32 + quad * 8]);
#pragma unroll
      for (int j = 0; j < 2; ++j)
        bf[j] = *(const frag16*)(&Bs[(wx * 32 + j * 16 + l15) * GP + ks * 32 + quad * 8]);
#pragma unroll
      for (int i = 0; i < 2; ++i)
#pragma unroll
        for (int j = 0; j < 2; ++j)
          acc[i][j] = __builtin_amdgcn_mfma_f32_16x16x32_bf16(af[i], bf[j], acc[i][j], 0, 0, 0);
    }
  }

  float bj[2];
#pragma unroll
  for (int j = 0; j < 2; ++j)
    bj[j] = bias[col0 + wx * 32 + j * 16 + l15];

#pragma unroll
  for (int i = 0; i < 2; ++i) {
#pragma unroll
    for (int rr = 0; rr < 4; ++rr) {
      const size_t row = row0 + wy * 32 + i * 16 + quad * 4 + rr;
#pragma unroll
      for (int j = 0; j < 2; ++j) {
        const float v = (acc[i][j][rr] + bj[j]) * oscale;
        const int col = col0 + wx * 32 + j * 16 + l15;
        if (out_mode == 0)      ((float*)Cout)[row * N + col] = v;
        else if (out_mode == 1) ((u16*)Cout)[row * N + col] = f2bf(v);
        else                    ((u16*)Cout)[(size_t)col * ldT + row] = f2bf(v);
      }
    }
  }
}

#define C2_SCALE 0.045084220027780106f   // log2(e)/32, folded into Q-proj

// blocks 0..511: Q-proj 128x64 tiles (inline fp32 A); 512..575: K-proj;
// 576..639: V-proj.
__global__ __launch_bounds__(256, 4)
void proj2(const float* __restrict__ query,
           const float* __restrict__ key, const float* __restrict__ value,
           const u16* __restrict__ wq_t, const u16* __restrict__ wk_t,
           const u16* __restrict__ wv_t,
           const float* __restrict__ bq, const float* __restrict__ bk,
           const float* __restrict__ bv,
           u16* __restrict__ q_bf, u16* __restrict__ k_bf,
           u16* __restrict__ vt_bf, int M, int K) {
  __shared__ __align__(16) u16 smem[12288];   // 24 KB
  const int bid = blockIdx.x;
  if (bid < 512)
    gemm128n64<true>(query, nullptr, wq_t, bq, q_bf, 1, C2_SCALE,
                     (bid >> 4) * 128, (bid & 15) * 64, 1024, K,
                     smem, smem + 8192);
  else if (bid < 576)
    gemm64<true>(key, nullptr, wk_t, bk, k_bf, 1, 1.0f,
                 (bid - 512) * 64, 0, 64, K, 0, smem, smem + 64 * GP);
  else
    gemm64<true>(value, nullptr, wv_t, bv, vt_bf, 2, 1.0f,
                 (bid - 576) * 64, 0, 64, K, M, smem, smem + 64 * GP);
}

__global__ __launch_bounds__(256, 4)
void out_proj(const u16* __restrict__ ao, const u16* __restrict__ wo_t,
              const float* __restrict__ bo, float* __restrict__ out,
              int M, int K) {
  __shared__ __align__(16) u16 smem[12288];
  const int bid = blockIdx.x;
  gemm128n64<false>(nullptr, ao, wo_t, bo, out, 0, 1.0f,
                    (bid >> 4) * 128, (bid & 15) * 64, 1024, K,
                    smem, smem + 8192);
}

// ---------------------------------------------------------------------------
// Flash MQA attention (R21-verified, FROZEN): 512-thread blocks = 8 waves =
// 8 heads sharing one staged K/V chunk. grid (S/32, H/8, B) = 256 blocks.
// Per-wave: R19 core (permlane-P, single-buffer 2-barrier, conflict-free).
// ---------------------------------------------------------------------------
#define PP 72

__global__ __launch_bounds__(512, 1)
void mqa_flash_mfma(const u16* __restrict__ Qb,  // [B,S,1024] bf16 (pre-scaled)
                    const u16* __restrict__ Kb,  // [B,S,64]   bf16
                    const u16* __restrict__ Vt,  // [64][B*S]  bf16 (transposed)
                    u16* __restrict__ O) {       // [B,S,1024] bf16
  const int S = 2048, HID = 1024, D = 64, BS = 4096;
  __shared__ __align__(16) u16 Kss[64 * PP];        // K[key][d]   9.2 KB
  __shared__ __align__(16) u16 Vss[64 * PP];        // V^T[d][key] 9.2 KB
  __shared__ float lred[8][32];

  const int tid  = threadIdx.x;
  const int lane = tid & 63;
  const int w    = tid >> 6;         // wave 0..7 = head offset
  const int l31  = lane & 31;
  const int hh   = lane >> 5;        // lane half (0/1)
  const int qb = blockIdx.x, hg = blockIdx.y, b = blockIdx.z;
  const int h = hg * 8 + w;          // this wave's head

  const int sr = tid >> 3;           // 0..63 staging row (one per thread)
  const int sc = (tid & 7) * 8;      // staging col (x8 u16)

  // Loop-invariant LDS bases.
  const u16* kfb0 = &Kss[l31 * PP + hh * 8];
  const u16* kfb1 = &Kss[(32 + l31) * PP + hh * 8];
  const u16* vfb0 = &Vss[l31 * PP + hh * 8];
  const u16* vfb1 = &Vss[(32 + l31) * PP + hh * 8];
  u16* kw = &Kss[sr * PP + sc];
  u16* vw = &Vss[sr * PP + sc];

  // Q B-frags: B[k=d][n=q]: q = qb*32+l31, d = ks*16 + 8*hh + j
  const u16* qrow = Qb + (size_t)(b * S + qb * 32 + l31) * HID + h * D;
  frag16 qf[4];
#pragma unroll
  for (int ks = 0; ks < 4; ++ks)
    qf[ks] = *(const frag16*)(qrow + ks * 16 + hh * 8);

  f32x16 zero16;
#pragma unroll
  for (int r = 0; r < 16; ++r) zero16[r] = 0.f;
  f32x16 oa0, oa1;
#pragma unroll
  for (int r = 0; r < 16; ++r) { oa0[r] = 0.f; oa1[r] = 0.f; }
  float l_lane = 0.f;

  const u16* kbase = Kb + (size_t)(b * S) * D;   // K[key][d]
  const u16* vbase = Vt + (size_t)(b * S);       // Vt[d][key]

  // ---- prologue: chunk 0 -> LDS; chunk 1 -> regs ----
  frag16 pk = *(const frag16*)(kbase + (size_t)sr * D + sc);
  frag16 pv = *(const frag16*)(vbase + (size_t)sr * BS + sc);
  *(frag16*)kw = pk;
  *(frag16*)vw = pv;
  pk = *(const frag16*)(kbase + (size_t)(64 + sr) * D + sc);
  pv = *(const frag16*)(vbase + (size_t)sr * BS + 64 + sc);
  __syncthreads();

  for (int kc = 0; kc < S; kc += 64) {
    // ---- 1. read all K/V frags of chunk t (loop-invariant addresses) ----
    frag16 kf0[4], kf1[4], vf0[4], vf1[4];
#pragma unroll
    for (int ks = 0; ks < 4; ++ks) {
      kf0[ks] = *(const frag16*)(kfb0 + ks * 16);
      kf1[ks] = *(const frag16*)(kfb1 + ks * 16);
      vf0[ks] = *(const frag16*)(vfb0 + ks * 16);
      vf1[ks] = *(const frag16*)(vfb1 + ks * 16);
    }
    __syncthreads();  // all waves done reading Kss/Vss

    // ---- 2. stage chunk t+1 (regs -> LDS) ----
    *(frag16*)kw = pk;
    *(frag16*)vw = pv;

    // ---- 3. issue global loads of chunk t+2 (clamped at tail) ----
    const int nc = (kc + 128 < S) ? kc + 128 : (S - 64);
    pk = *(const frag16*)(kbase + (size_t)(nc + sr) * D + sc);
    pv = *(const frag16*)(vbase + (size_t)sr * BS + nc + sc);

    // ---- 4. scores: sa0 (keys 0-31), sa1 (keys 32-63) ----
    f32x16 sa0, sa1;
#pragma unroll
    for (int ks = 0; ks < 4; ++ks)
      sa0 = __builtin_amdgcn_mfma_f32_32x32x16_bf16(kf0[ks], qf[ks], ks ? sa0 : zero16, 0, 0, 0);
#pragma unroll
    for (int ks = 0; ks < 4; ++ks)
      sa1 = __builtin_amdgcn_mfma_f32_32x32x16_bf16(kf1[ks], qf[ks], ks ? sa1 : zero16, 0, 0, 0);

    // ---- 5. softmax in-register: exp2 -> cvt_pk pairs ----
    u32 c0[4], c1[4], d0[4], d1[4];
#pragma unroll
    for (int g = 0; g < 4; ++g) {
      const float p0 = __builtin_amdgcn_exp2f(sa0[g * 4 + 0]);
      const float p1 = __builtin_amdgcn_exp2f(sa0[g * 4 + 1]);
      const float p2 = __builtin_amdgcn_exp2f(sa0[g * 4 + 2]);
      const float p3 = __builtin_amdgcn_exp2f(sa0[g * 4 + 3]);
      const float q0 = __builtin_amdgcn_exp2f(sa1[g * 4 + 0]);
      const float q1 = __builtin_amdgcn_exp2f(sa1[g * 4 + 1]);
      const float q2 = __builtin_amdgcn_exp2f(sa1[g * 4 + 2]);
      const float q3 = __builtin_amdgcn_exp2f(sa1[g * 4 + 3]);
      l_lane += ((p0 + p1) + (p2 + p3)) + ((q0 + q1) + (q2 + q3));
      c0[g] = cvt_pk_bf16(p0, p1); c1[g] = cvt_pk_bf16(p2, p3);
      d0[g] = cvt_pk_bf16(q0, q1); d1[g] = cvt_pk_bf16(q2, q3);
    }

    // ---- 6. build PV A-frags in-register (permlane32_swap, zero LDS) ----
    bf8u pa[4];
    pl32_swap(c0[0], c0[1]); pa[0].w[0] = c0[0]; pa[0].w[2] = c0[1];
    pl32_swap(c1[0], c1[1]); pa[0].w[1] = c1[0]; pa[0].w[3] = c1[1];
    pl32_swap(c0[2], c0[3]); pa[1].w[0] = c0[2]; pa[1].w[2] = c0[3];
    pl32_swap(c1[2], c1[3]); pa[1].w[1] = c1[2]; pa[1].w[3] = c1[3];
    pl32_swap(d0[0], d0[1]); pa[2].w[0] = d0[0]; pa[2].w[2] = d0[1];
    pl32_swap(d1[0], d1[1]); pa[2].w[1] = d1[0]; pa[2].w[3] = d1[1];
    pl32_swap(d0[2], d0[3]); pa[3].w[0] = d0[2]; pa[3].w[2] = d0[3];
    pl32_swap(d1[2], d1[3]); pa[3].w[1] = d1[2]; pa[3].w[3] = d1[3];

    // ---- 7. PV: A=pa regs, B=V frags; 2 d-halves ----
#pragma unroll
    for (int ks = 0; ks < 4; ++ks) {
      oa0 = __builtin_amdgcn_mfma_f32_32x32x16_bf16(pa[ks].v, vf0[ks], oa0, 0, 0, 0);
      oa1 = __builtin_amdgcn_mfma_f32_32x32x16_bf16(pa[ks].v, vf1[ks], oa1, 0, 0, 0);
    }

    __syncthreads();  // stage of chunk t+1 visible for next iteration's reads
  }

  // ---- l: lane + partner (complementary key-runs), wave-private broadcast ----
  l_lane += __shfl_xor(l_lane, 32);
  lred[w][l31] = l_lane;

  // ---- epilogue: O C-layout col=d (l31 / 32+l31), row q=(r&3)+8(r>>2)+4hh ----
#pragma unroll
  for (int g2 = 0; g2 < 4; ++g2) {
    const f32x4 lv = *(const f32x4*)(&lred[w][g2 * 8 + hh * 4]);
#pragma unroll
    for (int m = 0; m < 4; ++m) {
      const int r = g2 * 4 + m;
      const int q_local = g2 * 8 + hh * 4 + m;
      const float li = 1.f / lv[m];
      u16* orow = O + (size_t)(b * S + qb * 32 + q_local) * HID + h * D;
      orow[l31]      = f2bf(oa0[r] * li);
      orow[32 + l31] = f2bf(oa1[r] * li);
    }
  }
}

extern "C" void kernel_launch(void* const* d_in, const int* in_sizes, int n_in,
                              void* d_out, int out_size, void* d_ws, size_t ws_size,
                              hipStream_t stream) {
  const float* query = (const float*)d_in[0];
  const float* key   = (const float*)d_in[1];
  const float* value = (const float*)d_in[2];
  const float* Wq    = (const float*)d_in[3];
  const float* bq    = (const float*)d_in[4];
  const float* Wk    = (const float*)d_in[5];
  const float* bk    = (const float*)d_in[6];
  const float* Wv    = (const float*)d_in[7];
  const float* bv    = (const float*)d_in[8];
  const float* Wo    = (const float*)d_in[9];
  const float* bo    = (const float*)d_in[10];
  float* out = (float*)d_out;

  const int B = 2, S = 2048, IN = 1024, HID = 1024, H = 16, D = 64;
  const int M = B * S;  // 4096
  const size_t MB = 1024 * 1024;

  char* ws = (char*)d_ws;
  u16* q_bf  = (u16*)ws;                           // [0, 8MB)
  u16* ao_bf = (u16*)(ws + 8 * MB);                // [8, 16MB)  (mqa -> out_proj)
  u16* k_bf  = (u16*)(ws + 16 * MB);               // 0.5 MB
  u16* vt_bf = (u16*)(ws + 16 * MB + 512 * 1024);  // 0.5 MB
  u16* wq_t  = (u16*)(ws + 17 * MB);               // 2 MB [1024][1024]
  u16* wo_t  = (u16*)(ws + 19 * MB);               // 2 MB [1024][1024]
  u16* wk_t  = (u16*)(ws + 21 * MB);               // 128 KB [64][1024]
  u16* wv_t  = (u16*)(ws + 21 * MB + 128 * 1024);  // 128 KB [64][1024]

  dim3 blk(256);
  prep_w<<<dim3(544), blk, 0, stream>>>(Wq, Wo, Wk, Wv, wq_t, wo_t, wk_t, wv_t);
  proj2<<<dim3(640), blk, 0, stream>>>(query, key, value, wq_t, wk_t, wv_t,
                                       bq, bk, bv, q_bf, k_bf, vt_bf, M, IN);
  mqa_flash_mfma<<<dim3(S / 32, H / 8, B), dim3(512), 0, stream>>>(q_bf, k_bf, vt_bf, ao_bf);
  out_proj<<<dim3(512), blk, 0, stream>>>(ao_bf, wo_t, bo, out, M, HID);
}

// Round 19
// 200.230 us; speedup vs baseline: 1.0474x; 1.0474x over previous
//
#include <hip/hip_runtime.h>

// ---------------------------------------------------------------------------
// MQA: out = softmax((X Wq)(X Wk)^T / 32)(X Wv) Wo, MQA broadcast K/V.
// B=2, S=2048, IN=HID=1024, H=16, D=64.
// Round 27 (from R24 = 197.2us verified; R26 inline-fp32-A regressed ->
// reverted). Evidence: proj2 MfmaUtil 6%, HBM 29% of achievable, 2 blocks/CU
// -> GEMMs are CONCURRENCY-starved. The one GEMM lever that ever worked was
// the R11->R13 grid doubling (+8us). Apply it again: Q-proj/out_proj tiles
// 128x64 -> 64x64 (gemm64p = constant-halved R24-verified pipelined loop),
// grid 512 -> 1024 each = 4 blocks/CU = 16 waves/CU (2x latency hiding),
// LDS 16KB. Same staging/frag/epilogue algebra with halved strides.
// prep_w (1568, incl. xq_bf convert) / gemm64 / mqa (frozen R21) verbatim R24.
// ---------------------------------------------------------------------------

typedef unsigned int   u32;
typedef unsigned short u16;
typedef union { float4 v; float f[4]; } f4u;
typedef __attribute__((ext_vector_type(8)))  short frag16;  // 8 bf16 (4 VGPR)
typedef __attribute__((ext_vector_type(4)))  float f32x4;
typedef __attribute__((ext_vector_type(16))) float f32x16;  // 32x32 MFMA acc
typedef union { frag16 v; u32 w[4]; u16 e[8]; } bf8u;

static __device__ __forceinline__ u16 f2bf(float x) {
  union { float f; u32 u; } v; v.f = x;
  u32 r = v.u + 0x7fff + ((v.u >> 16) & 1);   // RNE
  return (u16)(r >> 16);
}

// HW packed f32x2 -> bf16x2 convert (RNE), inline asm (no builtin on gfx950).
static __device__ __forceinline__ u32 cvt_pk_bf16(float lo, float hi) {
  u32 r;
  asm("v_cvt_pk_bf16_f32 %0, %1, %2" : "=v"(r) : "v"(lo), "v"(hi));
  return r;
}

// In-place 32-lane-half swap (pure VALU, no LDS):
// after: a = [a_lo | b_lo], b = [a_hi | b_hi].  (R19-verified)
static __device__ __forceinline__ void pl32_swap(u32& a, u32& b) {
  asm volatile("v_permlane32_swap_b32 %0, %1" : "+v"(a), "+v"(b));
}

// Async global->LDS, 16B per lane. LDS dest = wave-uniform base + lane*16.
static __device__ __forceinline__ void gload_lds16(const u16* g, u16* l) {
  __builtin_amdgcn_global_load_lds(
      (const __attribute__((address_space(1))) u32*)g,
      (__attribute__((address_space(3))) u32*)l, 16, 0, 0);
}

// ---------------------------------------------------------------------------
// prep_w: weight transpose+convert tiles (blocks 0..543) + query fp32->bf16
// elementwise convert (blocks 544..1567; 4096 elems/block).  [R24 verbatim]
// ---------------------------------------------------------------------------
static __device__ void tcvt_tile(const float* __restrict__ src,
                                 u16* __restrict__ dst,
                                 int C, int ldT, int rt, int ct,
                                 float (*t)[65]) {
  const int r0 = rt * 64, c0 = ct * 64;
  const int tr  = threadIdx.x >> 4;
  const int tc4 = (threadIdx.x & 15) * 4;
#pragma unroll
  for (int i = 0; i < 4; ++i) {
    f4u v; v.v = *(const float4*)(src + (size_t)(r0 + tr + i * 16) * C + c0 + tc4);
    t[tr + i * 16][tc4 + 0] = v.f[0];
    t[tr + i * 16][tc4 + 1] = v.f[1];
    t[tr + i * 16][tc4 + 2] = v.f[2];
    t[tr + i * 16][tc4 + 3] = v.f[3];
  }
  __syncthreads();
#pragma unroll
  for (int i = 0; i < 4; ++i) {
    const int oc = tr + i * 16;
    ushort4 o;
    o.x = f2bf(t[tc4 + 0][oc]);
    o.y = f2bf(t[tc4 + 1][oc]);
    o.z = f2bf(t[tc4 + 2][oc]);
    o.w = f2bf(t[tc4 + 3][oc]);
    *(ushort4*)(dst + (size_t)(c0 + oc) * ldT + r0 + tc4) = o;
  }
}

__global__ __launch_bounds__(256)
void prep_w(const float* __restrict__ Wq, const float* __restrict__ Wo,
            const float* __restrict__ Wk, const float* __restrict__ Wv,
            const float* __restrict__ query,
            u16* __restrict__ wq_t, u16* __restrict__ wo_t,
            u16* __restrict__ wk_t, u16* __restrict__ wv_t,
            u16* __restrict__ xq_bf) {
  const int bid = blockIdx.x;
  if (bid >= 544) {
    const size_t base = (size_t)(bid - 544) * 4096 + threadIdx.x * 16;
    f4u x0, x1, x2, x3;
    x0.v = *(const float4*)(query + base);
    x1.v = *(const float4*)(query + base + 4);
    x2.v = *(const float4*)(query + base + 8);
    x3.v = *(const float4*)(query + base + 12);
    bf8u t0, t1;
    t0.w[0] = cvt_pk_bf16(x0.f[0], x0.f[1]);
    t0.w[1] = cvt_pk_bf16(x0.f[2], x0.f[3]);
    t0.w[2] = cvt_pk_bf16(x1.f[0], x1.f[1]);
    t0.w[3] = cvt_pk_bf16(x1.f[2], x1.f[3]);
    t1.w[0] = cvt_pk_bf16(x2.f[0], x2.f[1]);
    t1.w[1] = cvt_pk_bf16(x2.f[2], x2.f[3]);
    t1.w[2] = cvt_pk_bf16(x3.f[0], x3.f[1]);
    t1.w[3] = cvt_pk_bf16(x3.f[2], x3.f[3]);
    *(frag16*)(xq_bf + base)     = t0.v;
    *(frag16*)(xq_bf + base + 8) = t1.v;
    return;
  }
  __shared__ float t[64][65];
  if (bid < 256)      tcvt_tile(Wq, wq_t, 1024, 1024, bid >> 4, bid & 15, t);
  else if (bid < 512) tcvt_tile(Wo, wo_t, 1024, 1024, (bid - 256) >> 4, (bid - 256) & 15, t);
  else if (bid < 528) tcvt_tile(Wk, wk_t, 64, 1024, bid - 512, 0, t);
  else                tcvt_tile(Wv, wv_t, 64, 1024, bid - 528, 0, t);
}

// ---------------------------------------------------------------------------
// gemm64p: 64x64-tile bf16 GEMM, BK=64, pipelined K-loop (R24-verified shape,
// constants halved). C = A[M,K] . Bt[N,K]^T. 256 thr = 4 waves (2x2), each
// wave 32x32 out (2x2 16x16x32 frags). LDS: As[64][64] + Bs[64][64] = 16KB.
// Staging: A/B 2 segments per wave (seg = 8 rows x 64 cols = 1 wave-gload);
// wave w owns segs {2w, 2w+1} = rows w*16..w*16+16.
// ---------------------------------------------------------------------------
static __device__ void gemm64p(const u16* __restrict__ Abf,
                               const u16* __restrict__ Bt,
                               const float* __restrict__ bias,
                               void* __restrict__ Cout, int out_mode,
                               float oscale, int row0, int col0,
                               int N, int K, u16* As, u16* Bs) {
  const int tid  = threadIdx.x;
  const int lane = tid & 63;
  const int quad = lane >> 4, l15 = lane & 15;
  const int w = tid >> 6, wy = w >> 1, wx = w & 1;
  const int lrow = lane >> 3, lcol = (lane & 7) * 8;

  f32x4 acc[2][2];
#pragma unroll
  for (int i = 0; i < 2; ++i)
#pragma unroll
    for (int j = 0; j < 2; ++j) {
      acc[i][j][0] = 0.f; acc[i][j][1] = 0.f;
      acc[i][j][2] = 0.f; acc[i][j][3] = 0.f;
    }

  const u16* ag = Abf + (size_t)(row0 + w * 16 + lrow) * K + lcol;  // per-lane
  const u16* bg = Bt  + (size_t)(col0 + w * 16 + lrow) * K + lcol;
  u16* alds = As + w * 2 * 512;   // wave-uniform segment base (segs 2w, 2w+1)
  u16* blds = Bs + w * 2 * 512;

  // prologue: stage step 0
#pragma unroll
  for (int i = 0; i < 2; ++i) {
    gload_lds16(ag + (size_t)i * 8 * K, alds + i * 512);
    gload_lds16(bg + (size_t)i * 8 * K, blds + i * 512);
  }
  __syncthreads();   // step-0 staging visible

  for (int k0 = 0; k0 < K; k0 += 64) {
    // ---- 1. read all fragments of step t into registers ----
    frag16 af[2][2], bfr[2][2];
#pragma unroll
    for (int ks = 0; ks < 2; ++ks) {
#pragma unroll
      for (int i = 0; i < 2; ++i)
        af[ks][i] = *(const frag16*)(&As[(wy * 32 + i * 16 + l15) * 64 + ks * 32 + quad * 8]);
#pragma unroll
      for (int j = 0; j < 2; ++j)
        bfr[ks][j] = *(const frag16*)(&Bs[(wx * 32 + j * 16 + l15) * 64 + ks * 32 + quad * 8]);
    }
    __syncthreads();   // all waves done reading LDS (WAR for next stage)

    // ---- 2. issue next step's staging (latency hides under compute) ----
    if (k0 + 64 < K) {
#pragma unroll
      for (int i = 0; i < 2; ++i) {
        gload_lds16(ag + (size_t)i * 8 * K + k0 + 64, alds + i * 512);
        gload_lds16(bg + (size_t)i * 8 * K + k0 + 64, blds + i * 512);
      }
    }

    // ---- 3. compute from registers (no LDS access) ----
#pragma unroll
    for (int ks = 0; ks < 2; ++ks)
#pragma unroll
      for (int i = 0; i < 2; ++i)
#pragma unroll
        for (int j = 0; j < 2; ++j)
          acc[i][j] = __builtin_amdgcn_mfma_f32_16x16x32_bf16(af[ks][i], bfr[ks][j], acc[i][j], 0, 0, 0);

    __syncthreads();   // drains vmcnt -> step t+1 staged for next iteration
  }

  float bj[2];
#pragma unroll
  for (int j = 0; j < 2; ++j)
    bj[j] = bias[col0 + wx * 32 + j * 16 + l15];

#pragma unroll
  for (int i = 0; i < 2; ++i)
#pragma unroll
    for (int rr = 0; rr < 4; ++rr) {
      const size_t row = row0 + wy * 32 + i * 16 + quad * 4 + rr;
#pragma unroll
      for (int j = 0; j < 2; ++j) {
        const float v = (acc[i][j][rr] + bj[j]) * oscale;
        const int col = col0 + wx * 32 + j * 16 + l15;
        if (out_mode == 0) ((float*)Cout)[row * N + col] = v;
        else               ((u16*)Cout)[row * N + col] = f2bf(v);
      }
    }
}

// ---------------------------------------------------------------------------
// gemm64: 64x64-tile GEMM (kept for the N=64 K/V projections; fp32 A path).
// ---------------------------------------------------------------------------
#define GP 72
template <bool A_FP32>
static __device__ void gemm64(const float* __restrict__ Af32,
                              const u16* __restrict__ Abf,
                              const u16* __restrict__ Bt,
                              const float* __restrict__ bias,
                              void* __restrict__ Cout, int out_mode,
                              float oscale,
                              int row0, int col0, int N, int K, int ldT,
                              u16* As, u16* Bs) {
  const int tid  = threadIdx.x;
  const int lane = tid & 63;
  const int quad = lane >> 4, l15 = lane & 15;
  const int w = tid >> 6, wy = w >> 1, wx = w & 1;

  f32x4 acc[2][2];
#pragma unroll
  for (int i = 0; i < 2; ++i)
#pragma unroll
    for (int j = 0; j < 2; ++j) {
      acc[i][j][0] = 0.f; acc[i][j][1] = 0.f;
      acc[i][j][2] = 0.f; acc[i][j][3] = 0.f;
    }

  const int r = tid >> 2, c16 = (tid & 3) * 16;

  for (int k0 = 0; k0 < K; k0 += 64) {
    frag16 a0, a1;
    if (A_FP32) {
      const float* ap = Af32 + (size_t)(row0 + r) * K + k0 + c16;
      f4u x0, x1, x2, x3;
      x0.v = *(const float4*)(ap);
      x1.v = *(const float4*)(ap + 4);
      x2.v = *(const float4*)(ap + 8);
      x3.v = *(const float4*)(ap + 12);
      bf8u t0, t1;
      t0.w[0] = cvt_pk_bf16(x0.f[0], x0.f[1]);
      t0.w[1] = cvt_pk_bf16(x0.f[2], x0.f[3]);
      t0.w[2] = cvt_pk_bf16(x1.f[0], x1.f[1]);
      t0.w[3] = cvt_pk_bf16(x1.f[2], x1.f[3]);
      t1.w[0] = cvt_pk_bf16(x2.f[0], x2.f[1]);
      t1.w[1] = cvt_pk_bf16(x2.f[2], x2.f[3]);
      t1.w[2] = cvt_pk_bf16(x3.f[0], x3.f[1]);
      t1.w[3] = cvt_pk_bf16(x3.f[2], x3.f[3]);
      a0 = t0.v; a1 = t1.v;
    } else {
      const u16* ap = Abf + (size_t)(row0 + r) * K + k0 + c16;
      a0 = *(const frag16*)(ap);
      a1 = *(const frag16*)(ap + 8);
    }
    const u16* bp = Bt + (size_t)(col0 + r) * K + k0 + c16;
    const frag16 b0 = *(const frag16*)(bp);
    const frag16 b1 = *(const frag16*)(bp + 8);
    __syncthreads();
    *(frag16*)(&As[r * GP + c16])     = a0;
    *(frag16*)(&As[r * GP + c16 + 8]) = a1;
    *(frag16*)(&Bs[r * GP + c16])     = b0;
    *(frag16*)(&Bs[r * GP + c16 + 8]) = b1;
    __syncthreads();
#pragma unroll
    for (int ks = 0; ks < 2; ++ks) {
      frag16 af[2], bf[2];
#pragma unroll
      for (int i = 0; i < 2; ++i)
        af[i] = *(const frag16*)(&As[(wy * 32 + i * 16 + l15) * GP + ks * 32 + quad * 8]);
#pragma unroll
      for (int j = 0; j < 2; ++j)
        bf[j] = *(const frag16*)(&Bs[(wx * 32 + j * 16 + l15) * GP + ks * 32 + quad * 8]);
#pragma unroll
      for (int i = 0; i < 2; ++i)
#pragma unroll
        for (int j = 0; j < 2; ++j)
          acc[i][j] = __builtin_amdgcn_mfma_f32_16x16x32_bf16(af[i], bf[j], acc[i][j], 0, 0, 0);
    }
  }

  float bj[2];
#pragma unroll
  for (int j = 0; j < 2; ++j)
    bj[j] = bias[col0 + wx * 32 + j * 16 + l15];

#pragma unroll
  for (int i = 0; i < 2; ++i) {
#pragma unroll
    for (int rr = 0; rr < 4; ++rr) {
      const size_t row = row0 + wy * 32 + i * 16 + quad * 4 + rr;
#pragma unroll
      for (int j = 0; j < 2; ++j) {
        const float v = (acc[i][j][rr] + bj[j]) * oscale;
        const int col = col0 + wx * 32 + j * 16 + l15;
        if (out_mode == 0)      ((float*)Cout)[row * N + col] = v;
        else if (out_mode == 1) ((u16*)Cout)[row * N + col] = f2bf(v);
        else                    ((u16*)Cout)[(size_t)col * ldT + row] = f2bf(v);
      }
    }
  }
}

#define C2_SCALE 0.045084220027780106f   // log2(e)/32, folded into Q-proj

// blocks 0..1023: Q-proj 64x64 tiles; 1024..1087: K-proj; 1088..1151: V-proj.
__global__ __launch_bounds__(256, 4)
void proj2(const float* __restrict__ key, const float* __restrict__ value,
           const u16* __restrict__ xq_bf,
           const u16* __restrict__ wq_t, const u16* __restrict__ wk_t,
           const u16* __restrict__ wv_t,
           const float* __restrict__ bq, const float* __restrict__ bk,
           const float* __restrict__ bv,
           u16* __restrict__ q_bf, u16* __restrict__ k_bf,
           u16* __restrict__ vt_bf, int M, int K) {
  __shared__ __align__(16) u16 smem[12288];   // 24 KB (gemm64p uses 16 KB)
  const int bid = blockIdx.x;
  if (bid < 1024)
    gemm64p(xq_bf, wq_t, bq, q_bf, 1, C2_SCALE,
            (bid >> 4) * 64, (bid & 15) * 64, 1024, K, smem, smem + 4096);
  else if (bid < 1088)
    gemm64<true>(key, nullptr, wk_t, bk, k_bf, 1, 1.0f,
                 (bid - 1024) * 64, 0, 64, K, 0, smem, smem + 64 * GP);
  else
    gemm64<true>(value, nullptr, wv_t, bv, vt_bf, 2, 1.0f,
                 (bid - 1088) * 64, 0, 64, K, M, smem, smem + 64 * GP);
}

__global__ __launch_bounds__(256, 4)
void out_proj(const u16* __restrict__ ao, const u16* __restrict__ wo_t,
              const float* __restrict__ bo, float* __restrict__ out,
              int M, int K) {
  __shared__ __align__(16) u16 smem[8192];    // 16 KB
  const int bid = blockIdx.x;
  gemm64p(ao, wo_t, bo, out, 0, 1.0f,
          (bid >> 4) * 64, (bid & 15) * 64, 1024, K, smem, smem + 4096);
}

// ---------------------------------------------------------------------------
// Flash MQA attention (R21-verified, FROZEN): 512-thread blocks = 8 waves =
// 8 heads sharing one staged K/V chunk. grid (S/32, H/8, B) = 256 blocks.
// Per-wave: R19 core (permlane-P, single-buffer 2-barrier, conflict-free).
// ---------------------------------------------------------------------------
#define PP 72

__global__ __launch_bounds__(512, 1)
void mqa_flash_mfma(const u16* __restrict__ Qb,  // [B,S,1024] bf16 (pre-scaled)
                    const u16* __restrict__ Kb,  // [B,S,64]   bf16
                    const u16* __restrict__ Vt,  // [64][B*S]  bf16 (transposed)
                    u16* __restrict__ O) {       // [B,S,1024] bf16
  const int S = 2048, HID = 1024, D = 64, BS = 4096;
  __shared__ __align__(16) u16 Kss[64 * PP];        // K[key][d]   9.2 KB
  __shared__ __align__(16) u16 Vss[64 * PP];        // V^T[d][key] 9.2 KB
  __shared__ float lred[8][32];

  const int tid  = threadIdx.x;
  const int lane = tid & 63;
  const int w    = tid >> 6;         // wave 0..7 = head offset
  const int l31  = lane & 31;
  const int hh   = lane >> 5;        // lane half (0/1)
  const int qb = blockIdx.x, hg = blockIdx.y, b = blockIdx.z;
  const int h = hg * 8 + w;          // this wave's head

  const int sr = tid >> 3;           // 0..63 staging row (one per thread)
  const int sc = (tid & 7) * 8;      // staging col (x8 u16)

  // Loop-invariant LDS bases.
  const u16* kfb0 = &Kss[l31 * PP + hh * 8];
  const u16* kfb1 = &Kss[(32 + l31) * PP + hh * 8];
  const u16* vfb0 = &Vss[l31 * PP + hh * 8];
  const u16* vfb1 = &Vss[(32 + l31) * PP + hh * 8];
  u16* kw = &Kss[sr * PP + sc];
  u16* vw = &Vss[sr * PP + sc];

  // Q B-frags: B[k=d][n=q]: q = qb*32+l31, d = ks*16 + 8*hh + j
  const u16* qrow = Qb + (size_t)(b * S + qb * 32 + l31) * HID + h * D;
  frag16 qf[4];
#pragma unroll
  for (int ks = 0; ks < 4; ++ks)
    qf[ks] = *(const frag16*)(qrow + ks * 16 + hh * 8);

  f32x16 zero16;
#pragma unroll
  for (int r = 0; r < 16; ++r) zero16[r] = 0.f;
  f32x16 oa0, oa1;
#pragma unroll
  for (int r = 0; r < 16; ++r) { oa0[r] = 0.f; oa1[r] = 0.f; }
  float l_lane = 0.f;

  const u16* kbase = Kb + (size_t)(b * S) * D;   // K[key][d]
  const u16* vbase = Vt + (size_t)(b * S);       // Vt[d][key]

  // ---- prologue: chunk 0 -> LDS; chunk 1 -> regs ----
  frag16 pk = *(const frag16*)(kbase + (size_t)sr * D + sc);
  frag16 pv = *(const frag16*)(vbase + (size_t)sr * BS + sc);
  *(frag16*)kw = pk;
  *(frag16*)vw = pv;
  pk = *(const frag16*)(kbase + (size_t)(64 + sr) * D + sc);
  pv = *(const frag16*)(vbase + (size_t)sr * BS + 64 + sc);
  __syncthreads();

  for (int kc = 0; kc < S; kc += 64) {
    // ---- 1. read all K/V frags of chunk t (loop-invariant addresses) ----
    frag16 kf0[4], kf1[4], vf0[4], vf1[4];
#pragma unroll
    for (int ks = 0; ks < 4; ++ks) {
      kf0[ks] = *(const frag16*)(kfb0 + ks * 16);
      kf1[ks] = *(const frag16*)(kfb1 + ks * 16);
      vf0[ks] = *(const frag16*)(vfb0 + ks * 16);
      vf1[ks] = *(const frag16*)(vfb1 + ks * 16);
    }
    __syncthreads();  // all waves done reading Kss/Vss

    // ---- 2. stage chunk t+1 (regs -> LDS) ----
    *(frag16*)kw = pk;
    *(frag16*)vw = pv;

    // ---- 3. issue global loads of chunk t+2 (clamped at tail) ----
    const int nc = (kc + 128 < S) ? kc + 128 : (S - 64);
    pk = *(const frag16*)(kbase + (size_t)(nc + sr) * D + sc);
    pv = *(const frag16*)(vbase + (size_t)sr * BS + nc + sc);

    // ---- 4. scores: sa0 (keys 0-31), sa1 (keys 32-63) ----
    f32x16 sa0, sa1;
#pragma unroll
    for (int ks = 0; ks < 4; ++ks)
      sa0 = __builtin_amdgcn_mfma_f32_32x32x16_bf16(kf0[ks], qf[ks], ks ? sa0 : zero16, 0, 0, 0);
#pragma unroll
    for (int ks = 0; ks < 4; ++ks)
      sa1 = __builtin_amdgcn_mfma_f32_32x32x16_bf16(kf1[ks], qf[ks], ks ? sa1 : zero16, 0, 0, 0);

    // ---- 5. softmax in-register: exp2 -> cvt_pk pairs ----
    u32 c0[4], c1[4], d0[4], d1[4];
#pragma unroll
    for (int g = 0; g < 4; ++g) {
      const float p0 = __builtin_amdgcn_exp2f(sa0[g * 4 + 0]);
      const float p1 = __builtin_amdgcn_exp2f(sa0[g * 4 + 1]);
      const float p2 = __builtin_amdgcn_exp2f(sa0[g * 4 + 2]);
      const float p3 = __builtin_amdgcn_exp2f(sa0[g * 4 + 3]);
      const float q0 = __builtin_amdgcn_exp2f(sa1[g * 4 + 0]);
      const float q1 = __builtin_amdgcn_exp2f(sa1[g * 4 + 1]);
      const float q2 = __builtin_amdgcn_exp2f(sa1[g * 4 + 2]);
      const float q3 = __builtin_amdgcn_exp2f(sa1[g * 4 + 3]);
      l_lane += ((p0 + p1) + (p2 + p3)) + ((q0 + q1) + (q2 + q3));
      c0[g] = cvt_pk_bf16(p0, p1); c1[g] = cvt_pk_bf16(p2, p3);
      d0[g] = cvt_pk_bf16(q0, q1); d1[g] = cvt_pk_bf16(q2, q3);
    }

    // ---- 6. build PV A-frags in-register (permlane32_swap, zero LDS) ----
    bf8u pa[4];
    pl32_swap(c0[0], c0[1]); pa[0].w[0] = c0[0]; pa[0].w[2] = c0[1];
    pl32_swap(c1[0], c1[1]); pa[0].w[1] = c1[0]; pa[0].w[3] = c1[1];
    pl32_swap(c0[2], c0[3]); pa[1].w[0] = c0[2]; pa[1].w[2] = c0[3];
    pl32_swap(c1[2], c1[3]); pa[1].w[1] = c1[2]; pa[1].w[3] = c1[3];
    pl32_swap(d0[0], d0[1]); pa[2].w[0] = d0[0]; pa[2].w[2] = d0[1];
    pl32_swap(d1[0], d1[1]); pa[2].w[1] = d1[0]; pa[2].w[3] = d1[1];
    pl32_swap(d0[2], d0[3]); pa[3].w[0] = d0[2]; pa[3].w[2] = d0[3];
    pl32_swap(d1[2], d1[3]); pa[3].w[1] = d1[2]; pa[3].w[3] = d1[3];

    // ---- 7. PV: A=pa regs, B=V frags; 2 d-halves ----
#pragma unroll
    for (int ks = 0; ks < 4; ++ks) {
      oa0 = __builtin_amdgcn_mfma_f32_32x32x16_bf16(pa[ks].v, vf0[ks], oa0, 0, 0, 0);
      oa1 = __builtin_amdgcn_mfma_f32_32x32x16_bf16(pa[ks].v, vf1[ks], oa1, 0, 0, 0);
    }

    __syncthreads();  // stage of chunk t+1 visible for next iteration's reads
  }

  // ---- l: lane + partner (complementary key-runs), wave-private broadcast ----
  l_lane += __shfl_xor(l_lane, 32);
  lred[w][l31] = l_lane;

  // ---- epilogue: O C-layout col=d (l31 / 32+l31), row q=(r&3)+8(r>>2)+4hh ----
#pragma unroll
  for (int g2 = 0; g2 < 4; ++g2) {
    const f32x4 lv = *(const f32x4*)(&lred[w][g2 * 8 + hh * 4]);
#pragma unroll
    for (int m = 0; m < 4; ++m) {
      const int r = g2 * 4 + m;
      const int q_local = g2 * 8 + hh * 4 + m;
      const float li = 1.f / lv[m];
      u16* orow = O + (size_t)(b * S + qb * 32 + q_local) * HID + h * D;
      orow[l31]      = f2bf(oa0[r] * li);
      orow[32 + l31] = f2bf(oa1[r] * li);
    }
  }
}

extern "C" void kernel_launch(void* const* d_in, const int* in_sizes, int n_in,
                              void* d_out, int out_size, void* d_ws, size_t ws_size,
                              hipStream_t stream) {
  const float* query = (const float*)d_in[0];
  const float* key   = (const float*)d_in[1];
  const float* value = (const float*)d_in[2];
  const float* Wq    = (const float*)d_in[3];
  const float* bq    = (const float*)d_in[4];
  const float* Wk    = (const float*)d_in[5];
  const float* bk    = (const float*)d_in[6];
  const float* Wv    = (const float*)d_in[7];
  const float* bv    = (const float*)d_in[8];
  const float* Wo    = (const float*)d_in[9];
  const float* bo    = (const float*)d_in[10];
  float* out = (float*)d_out;

  const int B = 2, S = 2048, IN = 1024, HID = 1024, H = 16, D = 64;
  const int M = B * S;  // 4096
  const size_t MB = 1024 * 1024;

  char* ws = (char*)d_ws;
  u16* q_bf  = (u16*)ws;                           // [0, 8MB)
  u16* ao_bf = (u16*)(ws + 8 * MB);                // [8, 16MB)  (mqa -> out_proj)
  u16* xq_bf = ao_bf;                              // same slot (prep -> proj2)
  u16* k_bf  = (u16*)(ws + 16 * MB);               // 0.5 MB
  u16* vt_bf = (u16*)(ws + 16 * MB + 512 * 1024);  // 0.5 MB
  u16* wq_t  = (u16*)(ws + 17 * MB);               // 2 MB [1024][1024]
  u16* wo_t  = (u16*)(ws + 19 * MB);               // 2 MB [1024][1024]
  u16* wk_t  = (u16*)(ws + 21 * MB);               // 128 KB [64][1024]
  u16* wv_t  = (u16*)(ws + 21 * MB + 128 * 1024);  // 128 KB [64][1024]

  dim3 blk(256);
  prep_w<<<dim3(1568), blk, 0, stream>>>(Wq, Wo, Wk, Wv, query,
                                         wq_t, wo_t, wk_t, wv_t, xq_bf);
  proj2<<<dim3(1152), blk, 0, stream>>>(key, value, xq_bf, wq_t, wk_t, wv_t,
                                        bq, bk, bv, q_bf, k_bf, vt_bf, M, IN);
  mqa_flash_mfma<<<dim3(S / 32, H / 8, B), dim3(512), 0, stream>>>(q_bf, k_bf, vt_bf, ao_bf);
  out_proj<<<dim3(1024), blk, 0, stream>>>(ao_bf, wo_t, bo, out, M, HID);
}

// Round 20
// 197.818 us; speedup vs baseline: 1.0601x; 1.0122x over previous
//
#include <hip/hip_runtime.h>

// ---------------------------------------------------------------------------
// MQA: out = softmax((X Wq)(X Wk)^T / 32)(X Wv) Wo, MQA broadcast K/V.
// B=2, S=2048, IN=HID=1024, H=16, D=64.
// Round 28 (from R24 = 197.2us verified; R27 64x64 grid-doubling neutral ->
// reverted). Ledger: GEMM phases latency/launch-bound (~20% HBM, MfmaUtil
// 7%, FETCH ~= 1.2x compulsory); kernel-sum ~145us vs total ~200us -> ~50us
// of 4-deep launch serialization. Final contained lever: move the Wo
// transpose (consumed only by out_proj, two launches later) OFF the prep
// critical path into the mqa launch as 128 z==2 blocks (2 tiles per
// 512-thread block; LDS union; barrier counts match). Cross-kernel stream
// ordering guarantees wo_t visibility for out_proj. prep_w 1568 -> 1312.
// All compute bodies verbatim R24-verified (gemm128n64 pipelined, gemm64,
// mqa R21 core).
// ---------------------------------------------------------------------------

typedef unsigned int   u32;
typedef unsigned short u16;
typedef union { float4 v; float f[4]; } f4u;
typedef __attribute__((ext_vector_type(8)))  short frag16;  // 8 bf16 (4 VGPR)
typedef __attribute__((ext_vector_type(4)))  float f32x4;
typedef __attribute__((ext_vector_type(16))) float f32x16;  // 32x32 MFMA acc
typedef union { frag16 v; u32 w[4]; u16 e[8]; } bf8u;

static __device__ __forceinline__ u16 f2bf(float x) {
  union { float f; u32 u; } v; v.f = x;
  u32 r = v.u + 0x7fff + ((v.u >> 16) & 1);   // RNE
  return (u16)(r >> 16);
}

// HW packed f32x2 -> bf16x2 convert (RNE), inline asm (no builtin on gfx950).
static __device__ __forceinline__ u32 cvt_pk_bf16(float lo, float hi) {
  u32 r;
  asm("v_cvt_pk_bf16_f32 %0, %1, %2" : "=v"(r) : "v"(lo), "v"(hi));
  return r;
}

// In-place 32-lane-half swap (pure VALU, no LDS):
// after: a = [a_lo | b_lo], b = [a_hi | b_hi].  (R19-verified)
static __device__ __forceinline__ void pl32_swap(u32& a, u32& b) {
  asm volatile("v_permlane32_swap_b32 %0, %1" : "+v"(a), "+v"(b));
}

// Async global->LDS, 16B per lane. LDS dest = wave-uniform base + lane*16.
static __device__ __forceinline__ void gload_lds16(const u16* g, u16* l) {
  __builtin_amdgcn_global_load_lds(
      (const __attribute__((address_space(1))) u32*)g,
      (__attribute__((address_space(3))) u32*)l, 16, 0, 0);
}

// ---------------------------------------------------------------------------
// tcvt: 64x64 transpose+convert tile; tid passed explicitly so it can run
// as a half of a 512-thread block. One __syncthreads per call (barrier
// counts match across block halves).
// ---------------------------------------------------------------------------
static __device__ void tcvt_tile(const float* __restrict__ src,
                                 u16* __restrict__ dst,
                                 int C, int ldT, int rt, int ct,
                                 float (*t)[65], int tid) {
  const int r0 = rt * 64, c0 = ct * 64;
  const int tr  = tid >> 4;
  const int tc4 = (tid & 15) * 4;
#pragma unroll
  for (int i = 0; i < 4; ++i) {
    f4u v; v.v = *(const float4*)(src + (size_t)(r0 + tr + i * 16) * C + c0 + tc4);
    t[tr + i * 16][tc4 + 0] = v.f[0];
    t[tr + i * 16][tc4 + 1] = v.f[1];
    t[tr + i * 16][tc4 + 2] = v.f[2];
    t[tr + i * 16][tc4 + 3] = v.f[3];
  }
  __syncthreads();
#pragma unroll
  for (int i = 0; i < 4; ++i) {
    const int oc = tr + i * 16;
    ushort4 o;
    o.x = f2bf(t[tc4 + 0][oc]);
    o.y = f2bf(t[tc4 + 1][oc]);
    o.z = f2bf(t[tc4 + 2][oc]);
    o.w = f2bf(t[tc4 + 3][oc]);
    *(ushort4*)(dst + (size_t)(c0 + oc) * ldT + r0 + tc4) = o;
  }
}

// ---------------------------------------------------------------------------
// prep_w: Wq/Wk/Wv transposes + query fp32->bf16 convert. (Wo transpose
// moved into the mqa launch.) blocks: 0..255 Wq, 256..271 Wk, 272..287 Wv,
// 288..1311 xq convert (4096 elems/block).
// ---------------------------------------------------------------------------
__global__ __launch_bounds__(256)
void prep_w(const float* __restrict__ Wq, const float* __restrict__ Wk,
            const float* __restrict__ Wv, const float* __restrict__ query,
            u16* __restrict__ wq_t, u16* __restrict__ wk_t,
            u16* __restrict__ wv_t, u16* __restrict__ xq_bf) {
  const int bid = blockIdx.x;
  if (bid >= 288) {
    const size_t base = (size_t)(bid - 288) * 4096 + threadIdx.x * 16;
    f4u x0, x1, x2, x3;
    x0.v = *(const float4*)(query + base);
    x1.v = *(const float4*)(query + base + 4);
    x2.v = *(const float4*)(query + base + 8);
    x3.v = *(const float4*)(query + base + 12);
    bf8u t0, t1;
    t0.w[0] = cvt_pk_bf16(x0.f[0], x0.f[1]);
    t0.w[1] = cvt_pk_bf16(x0.f[2], x0.f[3]);
    t0.w[2] = cvt_pk_bf16(x1.f[0], x1.f[1]);
    t0.w[3] = cvt_pk_bf16(x1.f[2], x1.f[3]);
    t1.w[0] = cvt_pk_bf16(x2.f[0], x2.f[1]);
    t1.w[1] = cvt_pk_bf16(x2.f[2], x2.f[3]);
    t1.w[2] = cvt_pk_bf16(x3.f[0], x3.f[1]);
    t1.w[3] = cvt_pk_bf16(x3.f[2], x3.f[3]);
    *(frag16*)(xq_bf + base)     = t0.v;
    *(frag16*)(xq_bf + base + 8) = t1.v;
    return;
  }
  __shared__ float t[64][65];
  if (bid < 256)      tcvt_tile(Wq, wq_t, 1024, 1024, bid >> 4, bid & 15, t, threadIdx.x);
  else if (bid < 272) tcvt_tile(Wk, wk_t, 64, 1024, bid - 256, 0, t, threadIdx.x);
  else                tcvt_tile(Wv, wv_t, 64, 1024, bid - 272, 0, t, threadIdx.x);
}

// ---------------------------------------------------------------------------
// gemm128n64: 128x64-tile bf16 GEMM, BK=64, pipelined K-loop (R24-verified).
// C = A[M,K] . Bt[N,K]^T. 256 thr = 4 waves (2x2), wave 64x32 out.
// LDS: As[128][64] 16KB, Bs[64][64] 8KB, linear (global_load_lds dest).
// ---------------------------------------------------------------------------
static __device__ void gemm128n64(const u16* __restrict__ Abf,
                                  const u16* __restrict__ Bt,
                                  const float* __restrict__ bias,
                                  void* __restrict__ Cout, int out_mode,
                                  float oscale, int row0, int col0,
                                  int N, int K, u16* As, u16* Bs) {
  const int tid  = threadIdx.x;
  const int lane = tid & 63;
  const int quad = lane >> 4, l15 = lane & 15;
  const int w = tid >> 6, wy = w >> 1, wx = w & 1;
  const int lrow = lane >> 3, lcol = (lane & 7) * 8;

  f32x4 acc[4][2];
#pragma unroll
  for (int i = 0; i < 4; ++i)
#pragma unroll
    for (int j = 0; j < 2; ++j) {
      acc[i][j][0] = 0.f; acc[i][j][1] = 0.f;
      acc[i][j][2] = 0.f; acc[i][j][3] = 0.f;
    }

  const u16* ag = Abf + (size_t)(row0 + w * 32 + lrow) * K + lcol;  // per-lane
  const u16* bg = Bt  + (size_t)(col0 + w * 16 + lrow) * K + lcol;
  u16* alds = As + w * 4 * 512;   // wave-uniform segment base (A: segs 4w..4w+3)
  u16* blds = Bs + w * 2 * 512;   // B: segs 2w..2w+1

  // prologue: stage step 0
#pragma unroll
  for (int i = 0; i < 4; ++i)
    gload_lds16(ag + (size_t)i * 8 * K, alds + i * 512);
#pragma unroll
  for (int i = 0; i < 2; ++i)
    gload_lds16(bg + (size_t)i * 8 * K, blds + i * 512);
  __syncthreads();   // step-0 staging visible

  for (int k0 = 0; k0 < K; k0 += 64) {
    // ---- 1. read all fragments of step t into registers ----
    frag16 af[2][4], bfr[2][2];
#pragma unroll
    for (int ks = 0; ks < 2; ++ks) {
#pragma unroll
      for (int i = 0; i < 4; ++i)
        af[ks][i] = *(const frag16*)(&As[(wy * 64 + i * 16 + l15) * 64 + ks * 32 + quad * 8]);
#pragma unroll
      for (int j = 0; j < 2; ++j)
        bfr[ks][j] = *(const frag16*)(&Bs[(wx * 32 + j * 16 + l15) * 64 + ks * 32 + quad * 8]);
    }
    __syncthreads();   // all waves done reading LDS (WAR for next stage)

    // ---- 2. issue next step's staging (latency hides under compute) ----
    if (k0 + 64 < K) {
#pragma unroll
      for (int i = 0; i < 4; ++i)
        gload_lds16(ag + (size_t)i * 8 * K + k0 + 64, alds + i * 512);
#pragma unroll
      for (int i = 0; i < 2; ++i)
        gload_lds16(bg + (size_t)i * 8 * K + k0 + 64, blds + i * 512);
    }

    // ---- 3. compute from registers (no LDS access) ----
#pragma unroll
    for (int ks = 0; ks < 2; ++ks)
#pragma unroll
      for (int i = 0; i < 4; ++i)
#pragma unroll
        for (int j = 0; j < 2; ++j)
          acc[i][j] = __builtin_amdgcn_mfma_f32_16x16x32_bf16(af[ks][i], bfr[ks][j], acc[i][j], 0, 0, 0);

    __syncthreads();   // drains vmcnt -> step t+1 staged for next iteration
  }

  float bj[2];
#pragma unroll
  for (int j = 0; j < 2; ++j)
    bj[j] = bias[col0 + wx * 32 + j * 16 + l15];

#pragma unroll
  for (int i = 0; i < 4; ++i)
#pragma unroll
    for (int rr = 0; rr < 4; ++rr) {
      const size_t row = row0 + wy * 64 + i * 16 + quad * 4 + rr;
#pragma unroll
      for (int j = 0; j < 2; ++j) {
        const float v = (acc[i][j][rr] + bj[j]) * oscale;
        const int col = col0 + wx * 32 + j * 16 + l15;
        if (out_mode == 0) ((float*)Cout)[row * N + col] = v;
        else               ((u16*)Cout)[row * N + col] = f2bf(v);
      }
    }
}

// ---------------------------------------------------------------------------
// gemm64: 64x64-tile GEMM (kept for the N=64 K/V projections; fp32 A path).
// ---------------------------------------------------------------------------
#define GP 72
template <bool A_FP32>
static __device__ void gemm64(const float* __restrict__ Af32,
                              const u16* __restrict__ Abf,
                              const u16* __restrict__ Bt,
                              const float* __restrict__ bias,
                              void* __restrict__ Cout, int out_mode,
                              float oscale,
                              int row0, int col0, int N, int K, int ldT,
                              u16* As, u16* Bs) {
  const int tid  = threadIdx.x;
  const int lane = tid & 63;
  const int quad = lane >> 4, l15 = lane & 15;
  const int w = tid >> 6, wy = w >> 1, wx = w & 1;

  f32x4 acc[2][2];
#pragma unroll
  for (int i = 0; i < 2; ++i)
#pragma unroll
    for (int j = 0; j < 2; ++j) {
      acc[i][j][0] = 0.f; acc[i][j][1] = 0.f;
      acc[i][j][2] = 0.f; acc[i][j][3] = 0.f;
    }

  const int r = tid >> 2, c16 = (tid & 3) * 16;

  for (int k0 = 0; k0 < K; k0 += 64) {
    frag16 a0, a1;
    if (A_FP32) {
      const float* ap = Af32 + (size_t)(row0 + r) * K + k0 + c16;
      f4u x0, x1, x2, x3;
      x0.v = *(const float4*)(ap);
      x1.v = *(const float4*)(ap + 4);
      x2.v = *(const float4*)(ap + 8);
      x3.v = *(const float4*)(ap + 12);
      bf8u t0, t1;
      t0.w[0] = cvt_pk_bf16(x0.f[0], x0.f[1]);
      t0.w[1] = cvt_pk_bf16(x0.f[2], x0.f[3]);
      t0.w[2] = cvt_pk_bf16(x1.f[0], x1.f[1]);
      t0.w[3] = cvt_pk_bf16(x1.f[2], x1.f[3]);
      t1.w[0] = cvt_pk_bf16(x2.f[0], x2.f[1]);
      t1.w[1] = cvt_pk_bf16(x2.f[2], x2.f[3]);
      t1.w[2] = cvt_pk_bf16(x3.f[0], x3.f[1]);
      t1.w[3] = cvt_pk_bf16(x3.f[2], x3.f[3]);
      a0 = t0.v; a1 = t1.v;
    } else {
      const u16* ap = Abf + (size_t)(row0 + r) * K + k0 + c16;
      a0 = *(const frag16*)(ap);
      a1 = *(const frag16*)(ap + 8);
    }
    const u16* bp = Bt + (size_t)(col0 + r) * K + k0 + c16;
    const frag16 b0 = *(const frag16*)(bp);
    const frag16 b1 = *(const frag16*)(bp + 8);
    __syncthreads();
    *(frag16*)(&As[r * GP + c16])     = a0;
    *(frag16*)(&As[r * GP + c16 + 8]) = a1;
    *(frag16*)(&Bs[r * GP + c16])     = b0;
    *(frag16*)(&Bs[r * GP + c16 + 8]) = b1;
    __syncthreads();
#pragma unroll
    for (int ks = 0; ks < 2; ++ks) {
      frag16 af[2], bf[2];
#pragma unroll
      for (int i = 0; i < 2; ++i)
        af[i] = *(const frag16*)(&As[(wy * 32 + i * 16 + l15) * GP + ks * 32 + quad * 8]);
#pragma unroll
      for (int j = 0; j < 2; ++j)
        bf[j] = *(const frag16*)(&Bs[(wx * 32 + j * 16 + l15) * GP + ks * 32 + quad * 8]);
#pragma unroll
      for (int i = 0; i < 2; ++i)
#pragma unroll
        for (int j = 0; j < 2; ++j)
          acc[i][j] = __builtin_amdgcn_mfma_f32_16x16x32_bf16(af[i], bf[j], acc[i][j], 0, 0, 0);
    }
  }

  float bj[2];
#pragma unroll
  for (int j = 0; j < 2; ++j)
    bj[j] = bias[col0 + wx * 32 + j * 16 + l15];

#pragma unroll
  for (int i = 0; i < 2; ++i) {
#pragma unroll
    for (int rr = 0; rr < 4; ++rr) {
      const size_t row = row0 + wy * 32 + i * 16 + quad * 4 + rr;
#pragma unroll
      for (int j = 0; j < 2; ++j) {
        const float v = (acc[i][j][rr] + bj[j]) * oscale;
        const int col = col0 + wx * 32 + j * 16 + l15;
        if (out_mode == 0)      ((float*)Cout)[row * N + col] = v;
        else if (out_mode == 1) ((u16*)Cout)[row * N + col] = f2bf(v);
        else                    ((u16*)Cout)[(size_t)col * ldT + row] = f2bf(v);
      }
    }
  }
}

#define C2_SCALE 0.045084220027780106f   // log2(e)/32, folded into Q-proj

// blocks 0..511: Q-proj 128x64 tiles; 512..575: K-proj; 576..639: V-proj.
__global__ __launch_bounds__(256, 4)
void proj2(const float* __restrict__ key, const float* __restrict__ value,
           const u16* __restrict__ xq_bf,
           const u16* __restrict__ wq_t, const u16* __restrict__ wk_t,
           const u16* __restrict__ wv_t,
           const float* __restrict__ bq, const float* __restrict__ bk,
           const float* __restrict__ bv,
           u16* __restrict__ q_bf, u16* __restrict__ k_bf,
           u16* __restrict__ vt_bf, int M, int K) {
  __shared__ __align__(16) u16 smem[12288];   // 24 KB
  const int bid = blockIdx.x;
  if (bid < 512)
    gemm128n64(xq_bf, wq_t, bq, q_bf, 1, C2_SCALE,
               (bid >> 4) * 128, (bid & 15) * 64, 1024, K, smem, smem + 8192);
  else if (bid < 576)
    gemm64<true>(key, nullptr, wk_t, bk, k_bf, 1, 1.0f,
                 (bid - 512) * 64, 0, 64, K, 0, smem, smem + 64 * GP);
  else
    gemm64<true>(value, nullptr, wv_t, bv, vt_bf, 2, 1.0f,
                 (bid - 576) * 64, 0, 64, K, M, smem, smem + 64 * GP);
}

__global__ __launch_bounds__(256, 4)
void out_proj(const u16* __restrict__ ao, const u16* __restrict__ wo_t,
              const float* __restrict__ bo, float* __restrict__ out,
              int M, int K) {
  __shared__ __align__(16) u16 smem[12288];
  const int bid = blockIdx.x;
  gemm128n64(ao, wo_t, bo, out, 0, 1.0f,
             (bid >> 4) * 128, (bid & 15) * 64, 1024, K, smem, smem + 8192);
}

// ---------------------------------------------------------------------------
// Flash MQA attention (R21-verified core, FROZEN) + Wo-transpose side work:
// grid (S/32, H/8, B+1); z<2: 512-thread blocks = 8 waves = 8 heads sharing
// one staged K/V chunk (R19 core: permlane-P, single-buffer 2-barrier).
// z==2: each block transposes two 64x64 Wo tiles (halves of the block, LDS
// union; barrier counts match). wo_t consumed by out_proj (next launch).
// ---------------------------------------------------------------------------
#define PP 72

__global__ __launch_bounds__(512, 1)
void mqa_flash_mfma(const u16* __restrict__ Qb,  // [B,S,1024] bf16 (pre-scaled)
                    const u16* __restrict__ Kb,  // [B,S,64]   bf16
                    const u16* __restrict__ Vt,  // [64][B*S]  bf16 (transposed)
                    u16* __restrict__ O,         // [B,S,1024] bf16
                    const float* __restrict__ Wo,
                    u16* __restrict__ wo_t) {
  const int S = 2048, HID = 1024, D = 64, BS = 4096;
  __shared__ __align__(16) union {
    struct { u16 Kss[64 * PP]; u16 Vss[64 * PP]; float lred[8][32]; } m;
    float t[2][64][65];
  } sm;

  if (blockIdx.z == 2) {
    // ---- Wo transpose side work: 128 blocks x 2 tiles ----
    const int half = threadIdx.x >> 8;          // 0/1
    const int ltid = threadIdx.x & 255;
    const int tile = ((blockIdx.y * 64 + blockIdx.x) << 1) | half;  // 0..255
    tcvt_tile(Wo, wo_t, 1024, 1024, tile >> 4, tile & 15, sm.t[half], ltid);
    return;
  }

  u16* Kss = sm.m.Kss;
  u16* Vss = sm.m.Vss;
  float (*lred)[32] = sm.m.lred;

  const int tid  = threadIdx.x;
  const int lane = tid & 63;
  const int w    = tid >> 6;         // wave 0..7 = head offset
  const int l31  = lane & 31;
  const int hh   = lane >> 5;        // lane half (0/1)
  const int qb = blockIdx.x, hg = blockIdx.y, b = blockIdx.z;
  const int h = hg * 8 + w;          // this wave's head

  const int sr = tid >> 3;           // 0..63 staging row (one per thread)
  const int sc = (tid & 7) * 8;      // staging col (x8 u16)

  // Loop-invariant LDS bases.
  const u16* kfb0 = &Kss[l31 * PP + hh * 8];
  const u16* kfb1 = &Kss[(32 + l31) * PP + hh * 8];
  const u16* vfb0 = &Vss[l31 * PP + hh * 8];
  const u16* vfb1 = &Vss[(32 + l31) * PP + hh * 8];
  u16* kw = &Kss[sr * PP + sc];
  u16* vw = &Vss[sr * PP + sc];

  // Q B-frags: B[k=d][n=q]: q = qb*32+l31, d = ks*16 + 8*hh + j
  const u16* qrow = Qb + (size_t)(b * S + qb * 32 + l31) * HID + h * D;
  frag16 qf[4];
#pragma unroll
  for (int ks = 0; ks < 4; ++ks)
    qf[ks] = *(const frag16*)(qrow + ks * 16 + hh * 8);

  f32x16 zero16;
#pragma unroll
  for (int r = 0; r < 16; ++r) zero16[r] = 0.f;
  f32x16 oa0, oa1;
#pragma unroll
  for (int r = 0; r < 16; ++r) { oa0[r] = 0.f; oa1[r] = 0.f; }
  float l_lane = 0.f;

  const u16* kbase = Kb + (size_t)(b * S) * D;   // K[key][d]
  const u16* vbase = Vt + (size_t)(b * S);       // Vt[d][key]

  // ---- prologue: chunk 0 -> LDS; chunk 1 -> regs ----
  frag16 pk = *(const frag16*)(kbase + (size_t)sr * D + sc);
  frag16 pv = *(const frag16*)(vbase + (size_t)sr * BS + sc);
  *(frag16*)kw = pk;
  *(frag16*)vw = pv;
  pk = *(const frag16*)(kbase + (size_t)(64 + sr) * D + sc);
  pv = *(const frag16*)(vbase + (size_t)sr * BS + 64 + sc);
  __syncthreads();

  for (int kc = 0; kc < S; kc += 64) {
    // ---- 1. read all K/V frags of chunk t (loop-invariant addresses) ----
    frag16 kf0[4], kf1[4], vf0[4], vf1[4];
#pragma unroll
    for (int ks = 0; ks < 4; ++ks) {
      kf0[ks] = *(const frag16*)(kfb0 + ks * 16);
      kf1[ks] = *(const frag16*)(kfb1 + ks * 16);
      vf0[ks] = *(const frag16*)(vfb0 + ks * 16);
      vf1[ks] = *(const frag16*)(vfb1 + ks * 16);
    }
    __syncthreads();  // all waves done reading Kss/Vss

    // ---- 2. stage chunk t+1 (regs -> LDS) ----
    *(frag16*)kw = pk;
    *(frag16*)vw = pv;

    // ---- 3. issue global loads of chunk t+2 (clamped at tail) ----
    const int nc = (kc + 128 < S) ? kc + 128 : (S - 64);
    pk = *(const frag16*)(kbase + (size_t)(nc + sr) * D + sc);
    pv = *(const frag16*)(vbase + (size_t)sr * BS + nc + sc);

    // ---- 4. scores: sa0 (keys 0-31), sa1 (keys 32-63) ----
    f32x16 sa0, sa1;
#pragma unroll
    for (int ks = 0; ks < 4; ++ks)
      sa0 = __builtin_amdgcn_mfma_f32_32x32x16_bf16(kf0[ks], qf[ks], ks ? sa0 : zero16, 0, 0, 0);
#pragma unroll
    for (int ks = 0; ks < 4; ++ks)
      sa1 = __builtin_amdgcn_mfma_f32_32x32x16_bf16(kf1[ks], qf[ks], ks ? sa1 : zero16, 0, 0, 0);

    // ---- 5. softmax in-register: exp2 -> cvt_pk pairs ----
    u32 c0[4], c1[4], d0[4], d1[4];
#pragma unroll
    for (int g = 0; g < 4; ++g) {
      const float p0 = __builtin_amdgcn_exp2f(sa0[g * 4 + 0]);
      const float p1 = __builtin_amdgcn_exp2f(sa0[g * 4 + 1]);
      const float p2 = __builtin_amdgcn_exp2f(sa0[g * 4 + 2]);
      const float p3 = __builtin_amdgcn_exp2f(sa0[g * 4 + 3]);
      const float q0 = __builtin_amdgcn_exp2f(sa1[g * 4 + 0]);
      const float q1 = __builtin_amdgcn_exp2f(sa1[g * 4 + 1]);
      const float q2 = __builtin_amdgcn_exp2f(sa1[g * 4 + 2]);
      const float q3 = __builtin_amdgcn_exp2f(sa1[g * 4 + 3]);
      l_lane += ((p0 + p1) + (p2 + p3)) + ((q0 + q1) + (q2 + q3));
      c0[g] = cvt_pk_bf16(p0, p1); c1[g] = cvt_pk_bf16(p2, p3);
      d0[g] = cvt_pk_bf16(q0, q1); d1[g] = cvt_pk_bf16(q2, q3);
    }

    // ---- 6. build PV A-frags in-register (permlane32_swap, zero LDS) ----
    bf8u pa[4];
    pl32_swap(c0[0], c0[1]); pa[0].w[0] = c0[0]; pa[0].w[2] = c0[1];
    pl32_swap(c1[0], c1[1]); pa[0].w[1] = c1[0]; pa[0].w[3] = c1[1];
    pl32_swap(c0[2], c0[3]); pa[1].w[0] = c0[2]; pa[1].w[2] = c0[3];
    pl32_swap(c1[2], c1[3]); pa[1].w[1] = c1[2]; pa[1].w[3] = c1[3];
    pl32_swap(d0[0], d0[1]); pa[2].w[0] = d0[0]; pa[2].w[2] = d0[1];
    pl32_swap(d1[0], d1[1]); pa[2].w[1] = d1[0]; pa[2].w[3] = d1[1];
    pl32_swap(d0[2], d0[3]); pa[3].w[0] = d0[2]; pa[3].w[2] = d0[3];
    pl32_swap(d1[2], d1[3]); pa[3].w[1] = d1[2]; pa[3].w[3] = d1[3];

    // ---- 7. PV: A=pa regs, B=V frags; 2 d-halves ----
#pragma unroll
    for (int ks = 0; ks < 4; ++ks) {
      oa0 = __builtin_amdgcn_mfma_f32_32x32x16_bf16(pa[ks].v, vf0[ks], oa0, 0, 0, 0);
      oa1 = __builtin_amdgcn_mfma_f32_32x32x16_bf16(pa[ks].v, vf1[ks], oa1, 0, 0, 0);
    }

    __syncthreads();  // stage of chunk t+1 visible for next iteration's reads
  }

  // ---- l: lane + partner (complementary key-runs), wave-private broadcast ----
  l_lane += __shfl_xor(l_lane, 32);
  lred[w][l31] = l_lane;

  // ---- epilogue: O C-layout col=d (l31 / 32+l31), row q=(r&3)+8(r>>2)+4hh ----
#pragma unroll
  for (int g2 = 0; g2 < 4; ++g2) {
    const f32x4 lv = *(const f32x4*)(&lred[w][g2 * 8 + hh * 4]);
#pragma unroll
    for (int m = 0; m < 4; ++m) {
      const int r = g2 * 4 + m;
      const int q_local = g2 * 8 + hh * 4 + m;
      const float li = 1.f / lv[m];
      u16* orow = O + (size_t)(b * S + qb * 32 + q_local) * HID + h * D;
      orow[l31]      = f2bf(oa0[r] * li);
      orow[32 + l31] = f2bf(oa1[r] * li);
    }
  }
}

extern "C" void kernel_launch(void* const* d_in, const int* in_sizes, int n_in,
                              void* d_out, int out_size, void* d_ws, size_t ws_size,
                              hipStream_t stream) {
  const float* query = (const float*)d_in[0];
  const float* key   = (const float*)d_in[1];
  const float* value = (const float*)d_in[2];
  const float* Wq    = (const float*)d_in[3];
  const float* bq    = (const float*)d_in[4];
  const float* Wk    = (const float*)d_in[5];
  const float* bk    = (const float*)d_in[6];
  const float* Wv    = (const float*)d_in[7];
  const float* bv    = (const float*)d_in[8];
  const float* Wo    = (const float*)d_in[9];
  const float* bo    = (const float*)d_in[10];
  float* out = (float*)d_out;

  const int B = 2, S = 2048, IN = 1024, HID = 1024, H = 16, D = 64;
  const int M = B * S;  // 4096
  const size_t MB = 1024 * 1024;

  char* ws = (char*)d_ws;
  u16* q_bf  = (u16*)ws;                           // [0, 8MB)
  u16* ao_bf = (u16*)(ws + 8 * MB);                // [8, 16MB)  (mqa -> out_proj)
  u16* xq_bf = ao_bf;                              // same slot (prep -> proj2)
  u16* k_bf  = (u16*)(ws + 16 * MB);               // 0.5 MB
  u16* vt_bf = (u16*)(ws + 16 * MB + 512 * 1024);  // 0.5 MB
  u16* wq_t  = (u16*)(ws + 17 * MB);               // 2 MB [1024][1024]
  u16* wo_t  = (u16*)(ws + 19 * MB);               // 2 MB [1024][1024]
  u16* wk_t  = (u16*)(ws + 21 * MB);               // 128 KB [64][1024]
  u16* wv_t  = (u16*)(ws + 21 * MB + 128 * 1024);  // 128 KB [64][1024]

  dim3 blk(256);
  prep_w<<<dim3(1312), blk, 0, stream>>>(Wq, Wk, Wv, query,
                                         wq_t, wk_t, wv_t, xq_bf);
  proj2<<<dim3(640), blk, 0, stream>>>(key, value, xq_bf, wq_t, wk_t, wv_t,
                                       bq, bk, bv, q_bf, k_bf, vt_bf, M, IN);
  mqa_flash_mfma<<<dim3(S / 32, H / 8, B + 1), dim3(512), 0, stream>>>(
      q_bf, k_bf, vt_bf, ao_bf, Wo, wo_t);
  out_proj<<<dim3(512), blk, 0, stream>>>(ao_bf, wo_t, bo, out, M, HID);
}

// Round 21
// 195.380 us; speedup vs baseline: 1.0734x; 1.0125x over previous
//
#include <hip/hip_runtime.h>

// ---------------------------------------------------------------------------
// MQA: out = softmax((X Wq)(X Wk)^T / 32)(X Wv) Wo, MQA broadcast K/V.
// B=2, S=2048, IN=HID=1024, H=16, D=64.
// Round 29 (base = R24, best verified 197.2us; R28 work-shift neutral ->
// reverted): mqa barrier halving. R21's 8-head kernel used a single K/V
// buffer (2 barriers/chunk, 64 total). Replace with the R15-VERIFIED
// double-buffer scheme (1 barrier/chunk, 32 total): half t reads bufA and
// stages t+1 into bufB (disjoint -> no mid-barrier); the end-of-half
// barrier orders B-writes before the next half's B-reads and A-reads
// before the next half's A-writes. Loop unrolled x2 with NAMED buffer
// pointers (no runtime buffer index). Per-chunk compute/softmax/permlane
// algebra byte-identical to R21-verified. LDS 19.5 -> 38.4KB (grid-limited
// 1 block/CU regardless). prep_w / proj2 / out_proj verbatim R24.
// ---------------------------------------------------------------------------

typedef unsigned int   u32;
typedef unsigned short u16;
typedef union { float4 v; float f[4]; } f4u;
typedef __attribute__((ext_vector_type(8)))  short frag16;  // 8 bf16 (4 VGPR)
typedef __attribute__((ext_vector_type(4)))  float f32x4;
typedef __attribute__((ext_vector_type(16))) float f32x16;  // 32x32 MFMA acc
typedef union { frag16 v; u32 w[4]; u16 e[8]; } bf8u;

static __device__ __forceinline__ u16 f2bf(float x) {
  union { float f; u32 u; } v; v.f = x;
  u32 r = v.u + 0x7fff + ((v.u >> 16) & 1);   // RNE
  return (u16)(r >> 16);
}

// HW packed f32x2 -> bf16x2 convert (RNE), inline asm (no builtin on gfx950).
static __device__ __forceinline__ u32 cvt_pk_bf16(float lo, float hi) {
  u32 r;
  asm("v_cvt_pk_bf16_f32 %0, %1, %2" : "=v"(r) : "v"(lo), "v"(hi));
  return r;
}

// In-place 32-lane-half swap (pure VALU, no LDS):
// after: a = [a_lo | b_lo], b = [a_hi | b_hi].  (R19-verified)
static __device__ __forceinline__ void pl32_swap(u32& a, u32& b) {
  asm volatile("v_permlane32_swap_b32 %0, %1" : "+v"(a), "+v"(b));
}

// Async global->LDS, 16B per lane. LDS dest = wave-uniform base + lane*16.
static __device__ __forceinline__ void gload_lds16(const u16* g, u16* l) {
  __builtin_amdgcn_global_load_lds(
      (const __attribute__((address_space(1))) u32*)g,
      (__attribute__((address_space(3))) u32*)l, 16, 0, 0);
}

// ---------------------------------------------------------------------------
// prep_w: weight transpose+convert tiles (blocks 0..543) + query fp32->bf16
// elementwise convert (blocks 544..1567; 4096 elems/block).  [R24 verbatim]
// ---------------------------------------------------------------------------
static __device__ void tcvt_tile(const float* __restrict__ src,
                                 u16* __restrict__ dst,
                                 int C, int ldT, int rt, int ct,
                                 float (*t)[65]) {
  const int r0 = rt * 64, c0 = ct * 64;
  const int tr  = threadIdx.x >> 4;
  const int tc4 = (threadIdx.x & 15) * 4;
#pragma unroll
  for (int i = 0; i < 4; ++i) {
    f4u v; v.v = *(const float4*)(src + (size_t)(r0 + tr + i * 16) * C + c0 + tc4);
    t[tr + i * 16][tc4 + 0] = v.f[0];
    t[tr + i * 16][tc4 + 1] = v.f[1];
    t[tr + i * 16][tc4 + 2] = v.f[2];
    t[tr + i * 16][tc4 + 3] = v.f[3];
  }
  __syncthreads();
#pragma unroll
  for (int i = 0; i < 4; ++i) {
    const int oc = tr + i * 16;
    ushort4 o;
    o.x = f2bf(t[tc4 + 0][oc]);
    o.y = f2bf(t[tc4 + 1][oc]);
    o.z = f2bf(t[tc4 + 2][oc]);
    o.w = f2bf(t[tc4 + 3][oc]);
    *(ushort4*)(dst + (size_t)(c0 + oc) * ldT + r0 + tc4) = o;
  }
}

__global__ __launch_bounds__(256)
void prep_w(const float* __restrict__ Wq, const float* __restrict__ Wo,
            const float* __restrict__ Wk, const float* __restrict__ Wv,
            const float* __restrict__ query,
            u16* __restrict__ wq_t, u16* __restrict__ wo_t,
            u16* __restrict__ wk_t, u16* __restrict__ wv_t,
            u16* __restrict__ xq_bf) {
  const int bid = blockIdx.x;
  if (bid >= 544) {
    const size_t base = (size_t)(bid - 544) * 4096 + threadIdx.x * 16;
    f4u x0, x1, x2, x3;
    x0.v = *(const float4*)(query + base);
    x1.v = *(const float4*)(query + base + 4);
    x2.v = *(const float4*)(query + base + 8);
    x3.v = *(const float4*)(query + base + 12);
    bf8u t0, t1;
    t0.w[0] = cvt_pk_bf16(x0.f[0], x0.f[1]);
    t0.w[1] = cvt_pk_bf16(x0.f[2], x0.f[3]);
    t0.w[2] = cvt_pk_bf16(x1.f[0], x1.f[1]);
    t0.w[3] = cvt_pk_bf16(x1.f[2], x1.f[3]);
    t1.w[0] = cvt_pk_bf16(x2.f[0], x2.f[1]);
    t1.w[1] = cvt_pk_bf16(x2.f[2], x2.f[3]);
    t1.w[2] = cvt_pk_bf16(x3.f[0], x3.f[1]);
    t1.w[3] = cvt_pk_bf16(x3.f[2], x3.f[3]);
    *(frag16*)(xq_bf + base)     = t0.v;
    *(frag16*)(xq_bf + base + 8) = t1.v;
    return;
  }
  __shared__ float t[64][65];
  if (bid < 256)      tcvt_tile(Wq, wq_t, 1024, 1024, bid >> 4, bid & 15, t);
  else if (bid < 512) tcvt_tile(Wo, wo_t, 1024, 1024, (bid - 256) >> 4, (bid - 256) & 15, t);
  else if (bid < 528) tcvt_tile(Wk, wk_t, 64, 1024, bid - 512, 0, t);
  else                tcvt_tile(Wv, wv_t, 64, 1024, bid - 528, 0, t);
}

// ---------------------------------------------------------------------------
// gemm128n64: 128x64-tile bf16 GEMM, BK=64, pipelined K-loop (R24-verified).
// C = A[M,K] . Bt[N,K]^T. 256 thr = 4 waves (2x2), wave 64x32 out.
// LDS: As[128][64] 16KB, Bs[64][64] 8KB, linear (global_load_lds dest).
// ---------------------------------------------------------------------------
static __device__ void gemm128n64(const u16* __restrict__ Abf,
                                  const u16* __restrict__ Bt,
                                  const float* __restrict__ bias,
                                  void* __restrict__ Cout, int out_mode,
                                  float oscale, int row0, int col0,
                                  int N, int K, u16* As, u16* Bs) {
  const int tid  = threadIdx.x;
  const int lane = tid & 63;
  const int quad = lane >> 4, l15 = lane & 15;
  const int w = tid >> 6, wy = w >> 1, wx = w & 1;
  const int lrow = lane >> 3, lcol = (lane & 7) * 8;

  f32x4 acc[4][2];
#pragma unroll
  for (int i = 0; i < 4; ++i)
#pragma unroll
    for (int j = 0; j < 2; ++j) {
      acc[i][j][0] = 0.f; acc[i][j][1] = 0.f;
      acc[i][j][2] = 0.f; acc[i][j][3] = 0.f;
    }

  const u16* ag = Abf + (size_t)(row0 + w * 32 + lrow) * K + lcol;  // per-lane
  const u16* bg = Bt  + (size_t)(col0 + w * 16 + lrow) * K + lcol;
  u16* alds = As + w * 4 * 512;   // wave-uniform segment base (A: segs 4w..4w+3)
  u16* blds = Bs + w * 2 * 512;   // B: segs 2w..2w+1

  // prologue: stage step 0
#pragma unroll
  for (int i = 0; i < 4; ++i)
    gload_lds16(ag + (size_t)i * 8 * K, alds + i * 512);
#pragma unroll
  for (int i = 0; i < 2; ++i)
    gload_lds16(bg + (size_t)i * 8 * K, blds + i * 512);
  __syncthreads();   // step-0 staging visible

  for (int k0 = 0; k0 < K; k0 += 64) {
    // ---- 1. read all fragments of step t into registers ----
    frag16 af[2][4], bfr[2][2];
#pragma unroll
    for (int ks = 0; ks < 2; ++ks) {
#pragma unroll
      for (int i = 0; i < 4; ++i)
        af[ks][i] = *(const frag16*)(&As[(wy * 64 + i * 16 + l15) * 64 + ks * 32 + quad * 8]);
#pragma unroll
      for (int j = 0; j < 2; ++j)
        bfr[ks][j] = *(const frag16*)(&Bs[(wx * 32 + j * 16 + l15) * 64 + ks * 32 + quad * 8]);
    }
    __syncthreads();   // all waves done reading LDS (WAR for next stage)

    // ---- 2. issue next step's staging (latency hides under compute) ----
    if (k0 + 64 < K) {
#pragma unroll
      for (int i = 0; i < 4; ++i)
        gload_lds16(ag + (size_t)i * 8 * K + k0 + 64, alds + i * 512);
#pragma unroll
      for (int i = 0; i < 2; ++i)
        gload_lds16(bg + (size_t)i * 8 * K + k0 + 64, blds + i * 512);
    }

    // ---- 3. compute from registers (no LDS access) ----
#pragma unroll
    for (int ks = 0; ks < 2; ++ks)
#pragma unroll
      for (int i = 0; i < 4; ++i)
#pragma unroll
        for (int j = 0; j < 2; ++j)
          acc[i][j] = __builtin_amdgcn_mfma_f32_16x16x32_bf16(af[ks][i], bfr[ks][j], acc[i][j], 0, 0, 0);

    __syncthreads();   // drains vmcnt -> step t+1 staged for next iteration
  }

  float bj[2];
#pragma unroll
  for (int j = 0; j < 2; ++j)
    bj[j] = bias[col0 + wx * 32 + j * 16 + l15];

#pragma unroll
  for (int i = 0; i < 4; ++i)
#pragma unroll
    for (int rr = 0; rr < 4; ++rr) {
      const size_t row = row0 + wy * 64 + i * 16 + quad * 4 + rr;
#pragma unroll
      for (int j = 0; j < 2; ++j) {
        const float v = (acc[i][j][rr] + bj[j]) * oscale;
        const int col = col0 + wx * 32 + j * 16 + l15;
        if (out_mode == 0) ((float*)Cout)[row * N + col] = v;
        else               ((u16*)Cout)[row * N + col] = f2bf(v);
      }
    }
}

// ---------------------------------------------------------------------------
// gemm64: 64x64-tile GEMM (kept for the N=64 K/V projections; fp32 A path).
// ---------------------------------------------------------------------------
#define GP 72
template <bool A_FP32>
static __device__ void gemm64(const float* __restrict__ Af32,
                              const u16* __restrict__ Abf,
                              const u16* __restrict__ Bt,
                              const float* __restrict__ bias,
                              void* __restrict__ Cout, int out_mode,
                              float oscale,
                              int row0, int col0, int N, int K, int ldT,
                              u16* As, u16* Bs) {
  const int tid  = threadIdx.x;
  const int lane = tid & 63;
  const int quad = lane >> 4, l15 = lane & 15;
  const int w = tid >> 6, wy = w >> 1, wx = w & 1;

  f32x4 acc[2][2];
#pragma unroll
  for (int i = 0; i < 2; ++i)
#pragma unroll
    for (int j = 0; j < 2; ++j) {
      acc[i][j][0] = 0.f; acc[i][j][1] = 0.f;
      acc[i][j][2] = 0.f; acc[i][j][3] = 0.f;
    }

  const int r = tid >> 2, c16 = (tid & 3) * 16;

  for (int k0 = 0; k0 < K; k0 += 64) {
    frag16 a0, a1;
    if (A_FP32) {
      const float* ap = Af32 + (size_t)(row0 + r) * K + k0 + c16;
      f4u x0, x1, x2, x3;
      x0.v = *(const float4*)(ap);
      x1.v = *(const float4*)(ap + 4);
      x2.v = *(const float4*)(ap + 8);
      x3.v = *(const float4*)(ap + 12);
      bf8u t0, t1;
      t0.w[0] = cvt_pk_bf16(x0.f[0], x0.f[1]);
      t0.w[1] = cvt_pk_bf16(x0.f[2], x0.f[3]);
      t0.w[2] = cvt_pk_bf16(x1.f[0], x1.f[1]);
      t0.w[3] = cvt_pk_bf16(x1.f[2], x1.f[3]);
      t1.w[0] = cvt_pk_bf16(x2.f[0], x2.f[1]);
      t1.w[1] = cvt_pk_bf16(x2.f[2], x2.f[3]);
      t1.w[2] = cvt_pk_bf16(x3.f[0], x3.f[1]);
      t1.w[3] = cvt_pk_bf16(x3.f[2], x3.f[3]);
      a0 = t0.v; a1 = t1.v;
    } else {
      const u16* ap = Abf + (size_t)(row0 + r) * K + k0 + c16;
      a0 = *(const frag16*)(ap);
      a1 = *(const frag16*)(ap + 8);
    }
    const u16* bp = Bt + (size_t)(col0 + r) * K + k0 + c16;
    const frag16 b0 = *(const frag16*)(bp);
    const frag16 b1 = *(const frag16*)(bp + 8);
    __syncthreads();
    *(frag16*)(&As[r * GP + c16])     = a0;
    *(frag16*)(&As[r * GP + c16 + 8]) = a1;
    *(frag16*)(&Bs[r * GP + c16])     = b0;
    *(frag16*)(&Bs[r * GP + c16 + 8]) = b1;
    __syncthreads();
#pragma unroll
    for (int ks = 0; ks < 2; ++ks) {
      frag16 af[2], bf[2];
#pragma unroll
      for (int i = 0; i < 2; ++i)
        af[i] = *(const frag16*)(&As[(wy * 32 + i * 16 + l15) * GP + ks * 32 + quad * 8]);
#pragma unroll
      for (int j = 0; j < 2; ++j)
        bf[j] = *(const frag16*)(&Bs[(wx * 32 + j * 16 + l15) * GP + ks * 32 + quad * 8]);
#pragma unroll
      for (int i = 0; i < 2; ++i)
#pragma unroll
        for (int j = 0; j < 2; ++j)
          acc[i][j] = __builtin_amdgcn_mfma_f32_16x16x32_bf16(af[i], bf[j], acc[i][j], 0, 0, 0);
    }
  }

  float bj[2];
#pragma unroll
  for (int j = 0; j < 2; ++j)
    bj[j] = bias[col0 + wx * 32 + j * 16 + l15];

#pragma unroll
  for (int i = 0; i < 2; ++i) {
#pragma unroll
    for (int rr = 0; rr < 4; ++rr) {
      const size_t row = row0 + wy * 32 + i * 16 + quad * 4 + rr;
#pragma unroll
      for (int j = 0; j < 2; ++j) {
        const float v = (acc[i][j][rr] + bj[j]) * oscale;
        const int col = col0 + wx * 32 + j * 16 + l15;
        if (out_mode == 0)      ((float*)Cout)[row * N + col] = v;
        else if (out_mode == 1) ((u16*)Cout)[row * N + col] = f2bf(v);
        else                    ((u16*)Cout)[(size_t)col * ldT + row] = f2bf(v);
      }
    }
  }
}

#define C2_SCALE 0.045084220027780106f   // log2(e)/32, folded into Q-proj

// blocks 0..511: Q-proj 128x64 tiles; 512..575: K-proj; 576..639: V-proj.
__global__ __launch_bounds__(256, 4)
void proj2(const float* __restrict__ key, const float* __restrict__ value,
           const u16* __restrict__ xq_bf,
           const u16* __restrict__ wq_t, const u16* __restrict__ wk_t,
           const u16* __restrict__ wv_t,
           const float* __restrict__ bq, const float* __restrict__ bk,
           const float* __restrict__ bv,
           u16* __restrict__ q_bf, u16* __restrict__ k_bf,
           u16* __restrict__ vt_bf, int M, int K) {
  __shared__ __align__(16) u16 smem[12288];   // 24 KB
  const int bid = blockIdx.x;
  if (bid < 512)
    gemm128n64(xq_bf, wq_t, bq, q_bf, 1, C2_SCALE,
               (bid >> 4) * 128, (bid & 15) * 64, 1024, K, smem, smem + 8192);
  else if (bid < 576)
    gemm64<true>(key, nullptr, wk_t, bk, k_bf, 1, 1.0f,
                 (bid - 512) * 64, 0, 64, K, 0, smem, smem + 64 * GP);
  else
    gemm64<true>(value, nullptr, wv_t, bv, vt_bf, 2, 1.0f,
                 (bid - 576) * 64, 0, 64, K, M, smem, smem + 64 * GP);
}

__global__ __launch_bounds__(256, 4)
void out_proj(const u16* __restrict__ ao, const u16* __restrict__ wo_t,
              const float* __restrict__ bo, float* __restrict__ out,
              int M, int K) {
  __shared__ __align__(16) u16 smem[12288];
  const int bid = blockIdx.x;
  gemm128n64(ao, wo_t, bo, out, 0, 1.0f,
             (bid >> 4) * 128, (bid & 15) * 64, 1024, K, smem, smem + 8192);
}

// ---------------------------------------------------------------------------
// Flash MQA attention v11: R21-verified per-chunk body + R15-verified
// double-buffer 1-barrier scheme. 512-thread blocks = 8 waves = 8 heads
// sharing one staged K/V chunk; grid (S/32, H/8, B) = 256 blocks.
// Loop unrolled x2 with named A/B buffers (no runtime buffer index).
// Per half (chunk c): read frags from CUR; stage regs(c+1) -> OTHER;
// load (c+2) -> regs; compute; ONE barrier.
// ---------------------------------------------------------------------------
#define PP 72

__global__ __launch_bounds__(512, 1)
void mqa_flash_mfma(const u16* __restrict__ Qb,  // [B,S,1024] bf16 (pre-scaled)
                    const u16* __restrict__ Kb,  // [B,S,64]   bf16
                    const u16* __restrict__ Vt,  // [64][B*S]  bf16 (transposed)
                    u16* __restrict__ O) {       // [B,S,1024] bf16
  const int S = 2048, HID = 1024, D = 64, BS = 4096;
  __shared__ __align__(16) u16 KssA[64 * PP];       // buffers: 4 x 9.2 KB
  __shared__ __align__(16) u16 VssA[64 * PP];
  __shared__ __align__(16) u16 KssB[64 * PP];
  __shared__ __align__(16) u16 VssB[64 * PP];
  __shared__ float lred[8][32];

  const int tid  = threadIdx.x;
  const int lane = tid & 63;
  const int w    = tid >> 6;         // wave 0..7 = head offset
  const int l31  = lane & 31;
  const int hh   = lane >> 5;        // lane half (0/1)
  const int qb = blockIdx.x, hg = blockIdx.y, b = blockIdx.z;
  const int h = hg * 8 + w;          // this wave's head

  const int sr = tid >> 3;           // 0..63 staging row (one per thread)
  const int sc = (tid & 7) * 8;      // staging col (x8 u16)

  // Loop-invariant LDS bases, both buffers.
  const u16* kfA0 = &KssA[l31 * PP + hh * 8];
  const u16* kfA1 = &KssA[(32 + l31) * PP + hh * 8];
  const u16* vfA0 = &VssA[l31 * PP + hh * 8];
  const u16* vfA1 = &VssA[(32 + l31) * PP + hh * 8];
  const u16* kfB0 = &KssB[l31 * PP + hh * 8];
  const u16* kfB1 = &KssB[(32 + l31) * PP + hh * 8];
  const u16* vfB0 = &VssB[l31 * PP + hh * 8];
  const u16* vfB1 = &VssB[(32 + l31) * PP + hh * 8];
  u16* kwA = &KssA[sr * PP + sc];
  u16* vwA = &VssA[sr * PP + sc];
  u16* kwB = &KssB[sr * PP + sc];
  u16* vwB = &VssB[sr * PP + sc];

  // Q B-frags: B[k=d][n=q]: q = qb*32+l31, d = ks*16 + 8*hh + j
  const u16* qrow = Qb + (size_t)(b * S + qb * 32 + l31) * HID + h * D;
  frag16 qf[4];
#pragma unroll
  for (int ks = 0; ks < 4; ++ks)
    qf[ks] = *(const frag16*)(qrow + ks * 16 + hh * 8);

  f32x16 zero16;
#pragma unroll
  for (int r = 0; r < 16; ++r) zero16[r] = 0.f;
  f32x16 oa0, oa1;
#pragma unroll
  for (int r = 0; r < 16; ++r) { oa0[r] = 0.f; oa1[r] = 0.f; }
  float l_lane = 0.f;

  const u16* kbase = Kb + (size_t)(b * S) * D;   // K[key][d]
  const u16* vbase = Vt + (size_t)(b * S);       // Vt[d][key]

  // Prefetch registers (t+2 deep, as R21).
  frag16 pk, pv;

  // ---- prologue: chunk 0 -> bufA; chunk 1 -> regs ----
  pk = *(const frag16*)(kbase + (size_t)sr * D + sc);
  pv = *(const frag16*)(vbase + (size_t)sr * BS + sc);
  *(frag16*)kwA = pk;
  *(frag16*)vwA = pv;
  pk = *(const frag16*)(kbase + (size_t)(64 + sr) * D + sc);
  pv = *(const frag16*)(vbase + (size_t)sr * BS + 64 + sc);
  __syncthreads();

  // Per-half body (R21-verified compute; dbuf staging; one barrier).
#define MQA_HALF(KF0, KF1, VF0, VF1, KWN, VWN, CHUNK)                          \
  {                                                                            \
    frag16 kf0[4], kf1[4], vf0[4], vf1[4];                                     \
    _Pragma("unroll")                                                          \
    for (int ks = 0; ks < 4; ++ks) {                                           \
      kf0[ks] = *(const frag16*)(KF0 + ks * 16);                               \
      kf1[ks] = *(const frag16*)(KF1 + ks * 16);                               \
      vf0[ks] = *(const frag16*)(VF0 + ks * 16);                               \
      vf1[ks] = *(const frag16*)(VF1 + ks * 16);                               \
    }                                                                          \
    *(frag16*)KWN = pk;                                                        \
    *(frag16*)VWN = pv;                                                        \
    const int nc_ = ((CHUNK) + 128 < S) ? (CHUNK) + 128 : (S - 64);            \
    pk = *(const frag16*)(kbase + (size_t)(nc_ + sr) * D + sc);                \
    pv = *(const frag16*)(vbase + (size_t)sr * BS + nc_ + sc);                 \
    f32x16 sa0, sa1;                                                           \
    _Pragma("unroll")                                                          \
    for (int ks = 0; ks < 4; ++ks)                                             \
      sa0 = __builtin_amdgcn_mfma_f32_32x32x16_bf16(kf0[ks], qf[ks],           \
                ks ? sa0 : zero16, 0, 0, 0);                                   \
    _Pragma("unroll")                                                          \
    for (int ks = 0; ks < 4; ++ks)                                             \
      sa1 = __builtin_amdgcn_mfma_f32_32x32x16_bf16(kf1[ks], qf[ks],           \
                ks ? sa1 : zero16, 0, 0, 0);                                   \
    u32 c0[4], c1[4], d0[4], d1[4];                                            \
    _Pragma("unroll")                                                          \
    for (int g = 0; g < 4; ++g) {                                              \
      const float p0 = __builtin_amdgcn_exp2f(sa0[g * 4 + 0]);                 \
      const float p1 = __builtin_amdgcn_exp2f(sa0[g * 4 + 1]);                 \
      const float p2 = __builtin_amdgcn_exp2f(sa0[g * 4 + 2]);                 \
      const float p3 = __builtin_amdgcn_exp2f(sa0[g * 4 + 3]);                 \
      const float q0 = __builtin_amdgcn_exp2f(sa1[g * 4 + 0]);                 \
      const float q1 = __builtin_amdgcn_exp2f(sa1[g * 4 + 1]);                 \
      const float q2 = __builtin_amdgcn_exp2f(sa1[g * 4 + 2]);                 \
      const float q3 = __builtin_amdgcn_exp2f(sa1[g * 4 + 3]);                 \
      l_lane += ((p0 + p1) + (p2 + p3)) + ((q0 + q1) + (q2 + q3));             \
      c0[g] = cvt_pk_bf16(p0, p1); c1[g] = cvt_pk_bf16(p2, p3);                \
      d0[g] = cvt_pk_bf16(q0, q1); d1[g] = cvt_pk_bf16(q2, q3);                \
    }                                                                          \
    bf8u pa[4];                                                                \
    pl32_swap(c0[0], c0[1]); pa[0].w[0] = c0[0]; pa[0].w[2] = c0[1];           \
    pl32_swap(c1[0], c1[1]); pa[0].w[1] = c1[0]; pa[0].w[3] = c1[1];           \
    pl32_swap(c0[2], c0[3]); pa[1].w[0] = c0[2]; pa[1].w[2] = c0[3];           \
    pl32_swap(c1[2], c1[3]); pa[1].w[1] = c1[2]; pa[1].w[3] = c1[3];           \
    pl32_swap(d0[0], d0[1]); pa[2].w[0] = d0[0]; pa[2].w[2] = d0[1];           \
    pl32_swap(d1[0], d1[1]); pa[2].w[1] = d1[0]; pa[2].w[3] = d1[1];           \
    pl32_swap(d0[2], d0[3]); pa[3].w[0] = d0[2]; pa[3].w[2] = d0[3];           \
    pl32_swap(d1[2], d1[3]); pa[3].w[1] = d1[2]; pa[3].w[3] = d1[3];           \
    _Pragma("unroll")                                                          \
    for (int ks = 0; ks < 4; ++ks) {                                           \
      oa0 = __builtin_amdgcn_mfma_f32_32x32x16_bf16(pa[ks].v, vf0[ks], oa0,    \
                                                    0, 0, 0);                  \
      oa1 = __builtin_amdgcn_mfma_f32_32x32x16_bf16(pa[ks].v, vf1[ks], oa1,    \
                                                    0, 0, 0);                  \
    }                                                                          \
    __syncthreads();                                                           \
  }

  for (int kc = 0; kc < S; kc += 128) {
    // even chunk kc: read A, stage kc+1 -> B
    MQA_HALF(kfA0, kfA1, vfA0, vfA1, kwB, vwB, kc);
    // odd chunk kc+64: read B, stage kc+128 -> A
    MQA_HALF(kfB0, kfB1, vfB0, vfB1, kwA, vwA, kc + 64);
  }
#undef MQA_HALF

  // ---- l: lane + partner (complementary key-runs), wave-private broadcast ----
  l_lane += __shfl_xor(l_lane, 32);
  lred[w][l31] = l_lane;

  // ---- epilogue: O C-layout col=d (l31 / 32+l31), row q=(r&3)+8(r>>2)+4hh ----
#pragma unroll
  for (int g2 = 0; g2 < 4; ++g2) {
    const f32x4 lv = *(const f32x4*)(&lred[w][g2 * 8 + hh * 4]);
#pragma unroll
    for (int m = 0; m < 4; ++m) {
      const int r = g2 * 4 + m;
      const int q_local = g2 * 8 + hh * 4 + m;
      const float li = 1.f / lv[m];
      u16* orow = O + (size_t)(b * S + qb * 32 + q_local) * HID + h * D;
      orow[l31]      = f2bf(oa0[r] * li);
      orow[32 + l31] = f2bf(oa1[r] * li);
    }
  }
}

extern "C" void kernel_launch(void* const* d_in, const int* in_sizes, int n_in,
                              void* d_out, int out_size, void* d_ws, size_t ws_size,
                              hipStream_t stream) {
  const float* query = (const float*)d_in[0];
  const float* key   = (const float*)d_in[1];
  const float* value = (const float*)d_in[2];
  const float* Wq    = (const float*)d_in[3];
  const float* bq    = (const float*)d_in[4];
  const float* Wk    = (const float*)d_in[5];
  const float* bk    = (const float*)d_in[6];
  const float* Wv    = (const float*)d_in[7];
  const float* bv    = (const float*)d_in[8];
  const float* Wo    = (const float*)d_in[9];
  const float* bo    = (const float*)d_in[10];
  float* out = (float*)d_out;

  const int B = 2, S = 2048, IN = 1024, HID = 1024, H = 16, D = 64;
  const int M = B * S;  // 4096
  const size_t MB = 1024 * 1024;

  char* ws = (char*)d_ws;
  u16* q_bf  = (u16*)ws;                           // [0, 8MB)
  u16* ao_bf = (u16*)(ws + 8 * MB);                // [8, 16MB)  (mqa -> out_proj)
  u16* xq_bf = ao_bf;                              // same slot (prep -> proj2)
  u16* k_bf  = (u16*)(ws + 16 * MB);               // 0.5 MB
  u16* vt_bf = (u16*)(ws + 16 * MB + 512 * 1024);  // 0.5 MB
  u16* wq_t  = (u16*)(ws + 17 * MB);               // 2 MB [1024][1024]
  u16* wo_t  = (u16*)(ws + 19 * MB);               // 2 MB [1024][1024]
  u16* wk_t  = (u16*)(ws + 21 * MB);               // 128 KB [64][1024]
  u16* wv_t  = (u16*)(ws + 21 * MB + 128 * 1024);  // 128 KB [64][1024]

  dim3 blk(256);
  prep_w<<<dim3(1568), blk, 0, stream>>>(Wq, Wo, Wk, Wv, query,
                                         wq_t, wo_t, wk_t, wv_t, xq_bf);
  proj2<<<dim3(640), blk, 0, stream>>>(key, value, xq_bf, wq_t, wk_t, wv_t,
                                       bq, bk, bv, q_bf, k_bf, vt_bf, M, IN);
  mqa_flash_mfma<<<dim3(S / 32, H / 8, B), dim3(512), 0, stream>>>(q_bf, k_bf, vt_bf, ao_bf);
  out_proj<<<dim3(512), blk, 0, stream>>>(ao_bf, wo_t, bo, out, M, HID);
}